// Round 13
// baseline (3202.277 us; speedup 1.0000x reference)
//
#include <hip/hip_runtime.h>
#include <math.h>

// FCM mutual-kNN attention mixing. N=8192, D=256, K=16.
//   K1 prep:   feats->bf16, row sqnorms, zero cnt_g
//   K1b stats: deterministic reduction of sq -> mu/var
//   K2 gemm:   32 rows/block, A fully in VGPRs, B streamed global->reg ring
//              (depth-2 prefetch), ZERO LDS/barriers in main loop; threshold
//              select -> packed LDS cbuf -> one merge/block. 1024 blocks.
//   K2b fallback: detect + full-rescan repair of bad rows (expected none)
//   K3 refine: one wave/row, fp64 exact d2+dot over <=256 cands -> exact top-17
//   K4 out:    mutual mask + sparse softmax + mix + normalize
#define NPTS 8192
#define DIM  256
#define NSLOT 17
#define CAP  256
#define LCAP 48
#define ZTH  (-2.45f)
typedef unsigned int uint;
typedef unsigned short ushort;
typedef __attribute__((ext_vector_type(8))) short bf16x8;
typedef __attribute__((ext_vector_type(4))) float f32x4;

__device__ __forceinline__ ushort f2bf(float f) {
    uint x = __float_as_uint(f);
    return (ushort)((x + 0x7fffu + ((x >> 16) & 1u)) >> 16);
}

// ---------------- K1: bf16 copy + sqnorms + cnt_g=0 ----------------
__global__ void prep_kernel(const float* __restrict__ feats, ushort* __restrict__ fb,
                            float* __restrict__ sq, int* __restrict__ cnt_g) {
    const int row  = blockIdx.x * 4 + (threadIdx.x >> 6);
    const int lane = threadIdx.x & 63;
    const float4 v = *reinterpret_cast<const float4*>(feats + (size_t)row * DIM + lane * 4);
    ushort4 b; b.x = f2bf(v.x); b.y = f2bf(v.y); b.z = f2bf(v.z); b.w = f2bf(v.w);
    *reinterpret_cast<ushort4*>(fb + (size_t)row * DIM + lane * 4) = b;
    float p = v.x * v.x + v.y * v.y + v.z * v.z + v.w * v.w;
#pragma unroll
    for (int off = 32; off > 0; off >>= 1) p += __shfl_down(p, off, 64);
    if (lane == 0) { sq[row] = p; cnt_g[row] = 0; }
}

// ---------------- K1b: deterministic stats (mu, var) ----------------
__global__ void stats_kernel(const float* __restrict__ sq, float* __restrict__ musig) {
    __shared__ double s0s[16], s1s[16];
    const int t = threadIdx.x, lane = t & 63, w = t >> 6;
    double s0 = 0.0, s1 = 0.0;
    for (int r = t; r < NPTS; r += 1024) {
        const double v = (double)sq[r];
        s0 += v; s1 += v * v;
    }
#pragma unroll
    for (int off = 32; off > 0; off >>= 1) {
        s0 += __shfl_down(s0, off, 64);
        s1 += __shfl_down(s1, off, 64);
    }
    if (lane == 0) { s0s[w] = s0; s1s[w] = s1; }
    __syncthreads();
    if (t == 0) {
        double a0 = 0.0, a1 = 0.0;
#pragma unroll
        for (int q = 0; q < 16; ++q) { a0 += s0s[q]; a1 += s1s[q]; }
        const double mu = a0 / NPTS;
        const double var = a1 / NPTS - mu * mu;
        musig[0] = (float)mu;
        musig[1] = (float)fmax(var, 1.0);
    }
}

// ---------------- K2: reg-resident MFMA GEMM + fused threshold select ----------------
// 512 thr = 8 waves. Block: 32 rows x one 2048-col quarter (quarter pinned/XCD).
// Wave w owns cols w*32.. of each 256-col tile. A in regs, B depth-2 reg ring.
// No LDS and no barriers in the main loop.
__global__ __launch_bounds__(512, 2) void gemm_select_kernel(
    const ushort* __restrict__ fb, const float* __restrict__ sq,
    const float* __restrict__ musig, int* __restrict__ cand, int* __restrict__ cnt_g) {
    __shared__ int    cbuf[32][LCAP];    // 6 KB packed (keyq<<13)|idx
    __shared__ float  Ts[32], sqi_s[32];
    __shared__ int    cnt[32];
    __shared__ int    base_s[32], n_s[32];

    const int tid = threadIdx.x;
    const int w   = tid >> 6;
    const int l   = tid & 63;
    const int l15 = l & 15, lg = l >> 4;
    const int rowblk = (blockIdx.x >> 3) * 2 + (blockIdx.x & 1);
    const int row0   = rowblk * 32;
    const int Jbase  = ((blockIdx.x & 7) >> 1) * 2048;

    if (tid < 32) {
        const float mu  = musig[0];
        const float var = musig[1];
        const float qi  = sq[row0 + tid];
        sqi_s[tid] = qi;
        Ts[tid]    = qi + mu + ZTH * sqrtf(var + 4.f * qi);
        cnt[tid]   = 0;
    }

    // A resident: a[mf][ks] = F[row0 + mf*16 + l15][ks*32 + lg*8 .. +7]
    bf16x8 a[2][8];
#pragma unroll
    for (int mf = 0; mf < 2; ++mf) {
        const ushort* ap = fb + (size_t)(row0 + mf * 16 + l15) * DIM + lg * 8;
#pragma unroll
        for (int ks = 0; ks < 8; ++ks)
            a[mf][ks] = *reinterpret_cast<const bf16x8*>(ap + ks * 32);
    }
    __syncthreads();                     // Ts/cnt visible to all waves

    const int gcol = w * 32;
    const ushort* colp = fb + (size_t)(Jbase + gcol + l15) * DIM + lg * 8;
    // B for (chunk c = tile*8+ks, cf): colp + ((c>>3)*256 + cf*16)*DIM + (c&7)*32

    bf16x8 bb[3][2];
#pragma unroll
    for (int cf = 0; cf < 2; ++cf) {
        bb[0][cf] = *reinterpret_cast<const bf16x8*>(colp + (cf * 16) * DIM);
        bb[1][cf] = *reinterpret_cast<const bf16x8*>(colp + (cf * 16) * DIM + 32);
    }

    f32x4 acc[2][2];
#pragma unroll
    for (int mf = 0; mf < 2; ++mf)
#pragma unroll
        for (int cf = 0; cf < 2; ++cf) acc[mf][cf] = (f32x4){0.f, 0.f, 0.f, 0.f};

#pragma unroll
    for (int c = 0; c < 64; ++c) {       // fully unrolled: all bb indices static
        if (c + 2 < 64) {                // depth-2 prefetch into ring slot
            const int nt = (c + 2) >> 3, nk = (c + 2) & 7;
#pragma unroll
            for (int cf = 0; cf < 2; ++cf)
                bb[(c + 2) % 3][cf] = *reinterpret_cast<const bf16x8*>(
                    colp + (nt * 256 + cf * 16) * DIM + nk * 32);
        }
        const int ks = c & 7;
#pragma unroll
        for (int mf = 0; mf < 2; ++mf)
#pragma unroll
            for (int cf = 0; cf < 2; ++cf)
                acc[mf][cf] = __builtin_amdgcn_mfma_f32_16x16x32_bf16(
                    a[mf][ks], bb[c % 3][cf], acc[mf][cf], 0, 0, 0);
        if (ks == 7) {                   // ---- per-tile epilogue ----
            const int Jt = Jbase + (c >> 3) * 256;
            float sqc[2];
#pragma unroll
            for (int cf = 0; cf < 2; ++cf) sqc[cf] = sq[Jt + gcol + cf * 16 + l15];
#pragma unroll
            for (int mf = 0; mf < 2; ++mf)
#pragma unroll
                for (int cf = 0; cf < 2; ++cf)
#pragma unroll
                    for (int r = 0; r < 4; ++r) {
                        const int row = mf * 16 + lg * 4 + r;
                        const float tt = Ts[row];
                        const float key = sqi_s[row] + sqc[cf] - 2.f * acc[mf][cf][r];
                        if (key < tt) {
                            const int kq2 = min((int)((tt - key) * 4096.f), 524287);
                            const uint val = ((uint)max(kq2, 0) << 13) |
                                             (uint)(Jt + gcol + cf * 16 + l15);
                            const int pos = atomicAdd(&cnt[row], 1);
                            if (pos < LCAP) cbuf[row][pos] = (int)val;
                        }
                    }
#pragma unroll
            for (int mf = 0; mf < 2; ++mf)
#pragma unroll
                for (int cf = 0; cf < 2; ++cf) acc[mf][cf] = (f32x4){0.f, 0.f, 0.f, 0.f};
        }
    }
    __syncthreads();
    if (tid < 32) {
        const int local = cnt[tid];
        const int n = min(local, LCAP);
        const int add = (local > LCAP) ? (n + (1 << 20)) : n;   // poison on overflow
        base_s[tid] = atomicAdd(&cnt_g[row0 + tid], add);
        n_s[tid] = n;
    }
    __syncthreads();
    for (int s = tid; s < 32 * LCAP; s += 512) {
        const int r = s / LCAP, k2 = s - r * LCAP;
        if (k2 < n_s[r]) {
            const int b = base_s[r] + k2;
            if (b < CAP) cand[(size_t)(row0 + r) * CAP + b] = cbuf[r][k2];
        }
    }
}

// ---------------- K2b: detect + repair bad rows (expected none) ----------------
__global__ void fallback_kernel(const float* __restrict__ feats, const float* __restrict__ sq,
                                int* __restrict__ cand, int* __restrict__ cnt_g) {
    __shared__ float fi_s[DIM];
    __shared__ float keys[NPTS];
    __shared__ float rkey[4];
    __shared__ int   rid[4];
    const int t = threadIdx.x;
    for (int row = blockIdx.x; row < NPTS; row += gridDim.x) {
        const int v = cnt_g[row];
        if (v >= NSLOT && v <= CAP) continue;
        fi_s[t] = feats[(size_t)row * DIM + t];
        __syncthreads();
        const float sqi = sq[row];
        for (int p = 0; p < NPTS / 256; ++p) {
            const int jj = p * 256 + t;
            const float* fj = feats + (size_t)jj * DIM;
            float d = 0.f;
            for (int dq = 0; dq < DIM / 4; ++dq) {
                const float4 b4 = *reinterpret_cast<const float4*>(fj + dq * 4);
                const float4 a4 = *reinterpret_cast<const float4*>(&fi_s[dq * 4]);
                d = fmaf(a4.x, b4.x, fmaf(a4.y, b4.y, fmaf(a4.z, b4.z, fmaf(a4.w, b4.w, d))));
            }
            keys[jj] = sqi + sq[jj] - 2.f * d;
        }
        __syncthreads();
        for (int r = 0; r < 64; ++r) {
            float bk = INFINITY; int bj = 0x7fffffff;
            for (int p = 0; p < NPTS / 256; ++p) {
                const int jj = p * 256 + t;
                const float kv = keys[jj];
                if (kv < bk || (kv == bk && jj < bj)) { bk = kv; bj = jj; }
            }
#pragma unroll
            for (int off = 1; off <= 32; off <<= 1) {
                const float ok = __shfl_xor(bk, off, 64);
                const int   oj = __shfl_xor(bj, off, 64);
                if (ok < bk || (ok == bk && oj < bj)) { bk = ok; bj = oj; }
            }
            if ((t & 63) == 0) { rkey[t >> 6] = bk; rid[t >> 6] = bj; }
            __syncthreads();
            float fk = rkey[0]; int fj2 = rid[0];
#pragma unroll
            for (int q = 1; q < 4; ++q)
                if (rkey[q] < fk || (rkey[q] == fk && rid[q] < fj2)) { fk = rkey[q]; fj2 = rid[q]; }
            if (t == 0) {   // rank-ordered packed key (idx in low 13 bits)
                cand[(size_t)row * CAP + r] = (int)(((uint)(524287 - r) << 13) | (uint)fj2);
                keys[fj2] = INFINITY;
            }
            __syncthreads();
        }
        if (t == 0) cnt_g[row] = 64;
        __syncthreads();
    }
}

// ---------------- K3: fp64 refine, one wave per row -> exact top-17 ----------------
__global__ __launch_bounds__(256) void refine_kernel(
    const float* __restrict__ feats, const int* __restrict__ cand,
    const int* __restrict__ cnt_g, int* __restrict__ fidx, float* __restrict__ fscr) {
    __shared__ float fi_s[4][DIM];
    const int w = threadIdx.x >> 6, l = threadIdx.x & 63;
    const int i = blockIdx.x * 4 + w;
    *reinterpret_cast<float4*>(&fi_s[w][l * 4]) =
        *reinterpret_cast<const float4*>(feats + (size_t)i * DIM + l * 4);
    __syncthreads();                     // the only barrier; waves diverge after
    const int nc = min(cnt_g[i], CAP);
    double kdd[4]; int kj[4]; float kdot[4];
#pragma unroll
    for (int p = 0; p < 4; ++p) { kdd[p] = 1e300; kj[p] = 0x7fffffff; kdot[p] = 0.f; }
#pragma unroll
    for (int p = 0; p < 4; ++p) {
        const int c = p * 64 + l;
        if (c < nc) {
            const int j = cand[(size_t)i * CAP + c] & 8191;
            const float* fj = feats + (size_t)j * DIM;
            double dd = 0.0, dot = 0.0;
#pragma unroll 8
            for (int d = 0; d < DIM; d += 4) {
                const float4 b4 = *reinterpret_cast<const float4*>(fj + d);
                const float4 a4 = *reinterpret_cast<const float4*>(&fi_s[w][d]);
                const double dx = (double)a4.x - b4.x, dy = (double)a4.y - b4.y;
                const double dz = (double)a4.z - b4.z, dw2 = (double)a4.w - b4.w;
                dd  += dx * dx + dy * dy + dz * dz + dw2 * dw2;
                dot += (double)a4.x * b4.x + (double)a4.y * b4.y +
                       (double)a4.z * b4.z + (double)a4.w * b4.w;
            }
            kdd[p] = dd; kj[p] = j; kdot[p] = (float)dot;
        }
    }
    for (int r = 0; r < NSLOT; ++r) {
        double bk = kdd[0]; int bj = kj[0]; float bs = kdot[0];
#pragma unroll
        for (int p = 1; p < 4; ++p)
            if (kdd[p] < bk || (kdd[p] == bk && kj[p] < bj)) { bk = kdd[p]; bj = kj[p]; bs = kdot[p]; }
#pragma unroll
        for (int off = 1; off <= 32; off <<= 1) {
            const double ok = __shfl_xor(bk, off, 64);
            const int    oj = __shfl_xor(bj, off, 64);
            const float  os = __shfl_xor(bs, off, 64);
            if (ok < bk || (ok == bk && oj < bj)) { bk = ok; bj = oj; bs = os; }
        }
        if (l == 0) { fidx[(size_t)i * NSLOT + r] = bj; fscr[(size_t)i * NSLOT + r] = bs; }
#pragma unroll
        for (int p = 0; p < 4; ++p) if (kj[p] == bj) kdd[p] = 1e300;
    }
}

// ---------------- K4: mutual mask + sparse softmax + mix + normalize ----------------
__global__ void fcm_out_kernel(const float* __restrict__ feats,
                               const int* __restrict__ knn_idx,
                               const float* __restrict__ knn_scr,
                               float* __restrict__ out) {
    const int w    = threadIdx.x >> 6;
    const int lane = threadIdx.x & 63;
    const int i    = blockIdx.x * 4 + w;

    int jt = -1; float st = 0.f; bool valid = false;
    if (lane < NSLOT) {
        jt = knn_idx[(size_t)i * NSLOT + lane];
        st = knn_scr[(size_t)i * NSLOT + lane];
        if (jt != i) {
            const int* nb = knn_idx + (size_t)jt * NSLOT;
#pragma unroll
            for (int s = 0; s < NSLOT; ++s) valid |= (nb[s] == i);
        }
    }
    float val = valid ? st : -INFINITY;
#pragma unroll
    for (int off = 32; off > 0; off >>= 1) val = fmaxf(val, __shfl_xor(val, off, 64));
    const float m  = fmaxf(1.0f, val);
    const float wt = valid ? expf(st - m) : 0.f;
    float ws = wt;
#pragma unroll
    for (int off = 32; off > 0; off >>= 1) ws += __shfl_xor(ws, off, 64);
    const float wdiag = expf(1.0f - m);
    const float inv   = 1.0f / (ws + wdiag);

    const float4 fi = *reinterpret_cast<const float4*>(feats + (size_t)i * DIM + lane * 4);
    float ax = fi.x * wdiag, ay = fi.y * wdiag, az = fi.z * wdiag, aw = fi.w * wdiag;
    for (int t = 0; t < NSLOT; ++t) {
        const float wtt = __shfl(wt, t, 64);
        const int   jj  = __shfl(jt, t, 64);
        if (wtt > 0.f) {
            const float4 fj = *reinterpret_cast<const float4*>(feats + (size_t)jj * DIM + lane * 4);
            ax = fmaf(wtt, fj.x, ax); ay = fmaf(wtt, fj.y, ay);
            az = fmaf(wtt, fj.z, az); aw = fmaf(wtt, fj.w, aw);
        }
    }
    const float ox = fmaf(ax, inv, fi.x), oy = fmaf(ay, inv, fi.y);
    const float oz = fmaf(az, inv, fi.z), ow = fmaf(aw, inv, fi.w);
    float nn = ox * ox + oy * oy + oz * oz + ow * ow;
#pragma unroll
    for (int off = 32; off > 0; off >>= 1) nn += __shfl_xor(nn, off, 64);
    const float scl = 1.0f / fmaxf(sqrtf(nn), 1e-12f);
    float4 o; o.x = ox * scl; o.y = oy * scl; o.z = oz * scl; o.w = ow * scl;
    *reinterpret_cast<float4*>(out + (size_t)i * DIM + lane * 4) = o;
}

extern "C" void kernel_launch(void* const* d_in, const int* in_sizes, int n_in,
                              void* d_out, int out_size, void* d_ws, size_t ws_size,
                              hipStream_t stream) {
    (void)in_sizes; (void)n_in; (void)out_size; (void)ws_size;
    const float* feats = (const float*)d_in[0];
    float* out = (float*)d_out;
    char* ws = (char*)d_ws;
    size_t off = 0;
    float*  sq    = (float*) (ws + off); off += NPTS * 4;                 // 32 KB
    float*  musig = (float*) (ws + off); off += 128;
    ushort* fb    = (ushort*)(ws + off); off += (size_t)NPTS * DIM * 2;   // 4 MB
    int*    cand  = (int*)   (ws + off); off += (size_t)NPTS * CAP * 4;   // 8 MB
    int*    cnt_g = (int*)   (ws + off); off += NPTS * 4;
    int*    fidx  = (int*)   (ws + off); off += NPTS * NSLOT * 4;
    float*  fscr  = (float*) (ws + off); off += NPTS * NSLOT * 4;

    prep_kernel<<<NPTS / 4, 256, 0, stream>>>(feats, fb, sq, cnt_g);
    stats_kernel<<<1, 1024, 0, stream>>>(sq, musig);
    gemm_select_kernel<<<(NPTS / 32) * 4, 512, 0, stream>>>(fb, sq, musig, cand, cnt_g);
    fallback_kernel<<<64, 256, 0, stream>>>(feats, sq, cand, cnt_g);
    refine_kernel<<<NPTS / 4, 256, 0, stream>>>(feats, cand, cnt_g, fidx, fscr);
    fcm_out_kernel<<<NPTS / 4, 256, 0, stream>>>(feats, fidx, fscr, out);
}

// Round 14
// 200.127 us; speedup vs baseline: 16.0013x; 16.0013x over previous
//
#include <hip/hip_runtime.h>
#include <math.h>

// FCM mutual-kNN attention mixing. N=8192, D=256, K=16.
//   K1 prep:   feats->bf16, row sqnorms, zero cnt_g
//   K1b stats: deterministic reduction of sq -> mu/var
//   K2 gemm:   A panel (64x256) in LDS (XOR swizzle), B streamed global->regs,
//              ZERO barriers in main loop; fused threshold select -> packed
//              (keyq<<13)|idx LDS cbuf -> one merge/block.  [round-12 verbatim]
//   K2b fallback: detect + full-rescan repair of bad rows (expected none)
//   K3 refine: top-24 preselect by packed key (in-reg) -> fp64 d2+dot (8 lanes
//              per cand) -> exact top-17. One wave per row.
//   K4 out:    mutual mask + sparse softmax + mix + normalize
#define NPTS 8192
#define DIM  256
#define NSLOT 17
#define CAP  256
#define LCAP 48
#define RSEL 24
#define ZTH  (-2.45f)
typedef unsigned int uint;
typedef unsigned short ushort;
typedef __attribute__((ext_vector_type(8))) short bf16x8;
typedef __attribute__((ext_vector_type(4))) float f32x4;

__device__ __forceinline__ ushort f2bf(float f) {
    uint x = __float_as_uint(f);
    return (ushort)((x + 0x7fffu + ((x >> 16) & 1u)) >> 16);
}

// ---------------- K1: bf16 copy + sqnorms + cnt_g=0 ----------------
__global__ void prep_kernel(const float* __restrict__ feats, ushort* __restrict__ fb,
                            float* __restrict__ sq, int* __restrict__ cnt_g) {
    const int row  = blockIdx.x * 4 + (threadIdx.x >> 6);
    const int lane = threadIdx.x & 63;
    const float4 v = *reinterpret_cast<const float4*>(feats + (size_t)row * DIM + lane * 4);
    ushort4 b; b.x = f2bf(v.x); b.y = f2bf(v.y); b.z = f2bf(v.z); b.w = f2bf(v.w);
    *reinterpret_cast<ushort4*>(fb + (size_t)row * DIM + lane * 4) = b;
    float p = v.x * v.x + v.y * v.y + v.z * v.z + v.w * v.w;
#pragma unroll
    for (int off = 32; off > 0; off >>= 1) p += __shfl_down(p, off, 64);
    if (lane == 0) { sq[row] = p; cnt_g[row] = 0; }
}

// ---------------- K1b: deterministic stats (mu, var) ----------------
__global__ void stats_kernel(const float* __restrict__ sq, float* __restrict__ musig) {
    __shared__ double s0s[16], s1s[16];
    const int t = threadIdx.x, lane = t & 63, w = t >> 6;
    double s0 = 0.0, s1 = 0.0;
    for (int r = t; r < NPTS; r += 1024) {
        const double v = (double)sq[r];
        s0 += v; s1 += v * v;
    }
#pragma unroll
    for (int off = 32; off > 0; off >>= 1) {
        s0 += __shfl_down(s0, off, 64);
        s1 += __shfl_down(s1, off, 64);
    }
    if (lane == 0) { s0s[w] = s0; s1s[w] = s1; }
    __syncthreads();
    if (t == 0) {
        double a0 = 0.0, a1 = 0.0;
#pragma unroll
        for (int q = 0; q < 16; ++q) { a0 += s0s[q]; a1 += s1s[q]; }
        const double mu = a0 / NPTS;
        const double var = a1 / NPTS - mu * mu;
        musig[0] = (float)mu;
        musig[1] = (float)fmax(var, 1.0);
    }
}

// ---------------- K2: barrier-free MFMA GEMM + fused threshold select ----------------
// [round-12 verbatim] 512 thr = 8 waves. Block: 64 rows x 2048-col quarter.
__global__ __launch_bounds__(512, 2) void gemm_select_kernel(
    const ushort* __restrict__ fb, const float* __restrict__ sq,
    const float* __restrict__ musig, int* __restrict__ cand, int* __restrict__ cnt_g) {
    __shared__ ushort As[64 * 256];      // 32 KB [row][k], byte ^= (row&7)<<4
    __shared__ int    cbuf[64][LCAP];    // 12 KB packed (keyq<<13)|idx
    __shared__ float  Ts[64], sqi_s[64];
    __shared__ int    cnt[64];
    __shared__ int    base_s[64], n_s[64];

    const int tid = threadIdx.x;
    const int w   = tid >> 6;
    const int l   = tid & 63;
    const int l15 = l & 15, lg = l >> 4;
    const int rowblk = (blockIdx.x >> 3) * 2 + (blockIdx.x & 1);
    const int row0   = rowblk * 64;
    const int Jbase  = ((blockIdx.x & 7) >> 1) * 2048;

    if (tid < 64) {
        const float mu  = musig[0];
        const float var = musig[1];
        const float qi  = sq[row0 + tid];
        sqi_s[tid] = qi;
        Ts[tid]    = qi + mu + ZTH * sqrtf(var + 4.f * qi);
        cnt[tid]   = 0;
    }
    {   // stage A panel once: 64 rows x 256 k
        const int row = tid >> 3, kq = tid & 7;
        const ushort* src = fb + (size_t)(row0 + row) * DIM;
        char* dst = reinterpret_cast<char*>(As);
        const int sw = (row & 7) << 4;
#pragma unroll
        for (int p = 0; p < 4; ++p) {
            const bf16x8 v = *reinterpret_cast<const bf16x8*>(src + (kq + p * 8) * 8);
            *reinterpret_cast<bf16x8*>(dst + ((row * 512 + (kq + p * 8) * 16) ^ sw)) = v;
        }
    }
    __syncthreads();                     // the ONLY barrier before the merge

    const int gcol = w * 32;
    const ushort* colp = fb + (size_t)(Jbase + gcol + l15) * DIM + lg * 8;

    bf16x8 bb[2][2];
#pragma unroll
    for (int cf = 0; cf < 2; ++cf)
        bb[0][cf] = *reinterpret_cast<const bf16x8*>(colp + cf * 16 * DIM);

    for (int tile = 0; tile < 8; ++tile) {
        f32x4 acc[4][2];
#pragma unroll
        for (int mf = 0; mf < 4; ++mf) {
            acc[mf][0] = (f32x4){0.f, 0.f, 0.f, 0.f};
            acc[mf][1] = (f32x4){0.f, 0.f, 0.f, 0.f};
        }
#pragma unroll
        for (int ks = 0; ks < 8; ++ks) {
            const int cur = ks & 1;
            if (tile < 7 || ks < 7) {
                const int ntile = (ks == 7) ? tile + 1 : tile;
                const int nks   = (ks == 7) ? 0 : ks + 1;
#pragma unroll
                for (int cf = 0; cf < 2; ++cf)
                    bb[cur ^ 1][cf] = *reinterpret_cast<const bf16x8*>(
                        colp + (ntile * 256 + cf * 16) * DIM + nks * 32);
            }
            bf16x8 af[4];
#pragma unroll
            for (int mf = 0; mf < 4; ++mf) {
                const int row = mf * 16 + l15;
                af[mf] = *reinterpret_cast<const bf16x8*>(
                    reinterpret_cast<const char*>(As) +
                    ((row * 512 + ks * 64 + lg * 16) ^ ((row & 7) << 4)));
            }
#pragma unroll
            for (int mf = 0; mf < 4; ++mf) {
                acc[mf][0] = __builtin_amdgcn_mfma_f32_16x16x32_bf16(af[mf], bb[cur][0], acc[mf][0], 0, 0, 0);
                acc[mf][1] = __builtin_amdgcn_mfma_f32_16x16x32_bf16(af[mf], bb[cur][1], acc[mf][1], 0, 0, 0);
            }
        }
        // ---- per-tile epilogue: threshold select, packed into LDS cbuf ----
        const int Jt = Jbase + tile * 256;
        float sqc[2];
#pragma unroll
        for (int cf = 0; cf < 2; ++cf) sqc[cf] = sq[Jt + gcol + cf * 16 + l15];
#pragma unroll
        for (int mf = 0; mf < 4; ++mf)
#pragma unroll
            for (int cf = 0; cf < 2; ++cf)
#pragma unroll
                for (int r = 0; r < 4; ++r) {
                    const int row = mf * 16 + lg * 4 + r;
                    const float tt = Ts[row];
                    const float key = sqi_s[row] + sqc[cf] - 2.f * acc[mf][cf][r];
                    if (key < tt) {
                        const int kq2 = min((int)((tt - key) * 4096.f), 524287);
                        const uint val = ((uint)max(kq2, 0) << 13) |
                                         (uint)(Jt + gcol + cf * 16 + l15);
                        const int pos = atomicAdd(&cnt[row], 1);
                        if (pos < LCAP) cbuf[row][pos] = (int)val;
                    }
                }
    }
    __syncthreads();
    if (tid < 64) {
        const int local = cnt[tid];
        const int n = min(local, LCAP);
        const int add = (local > LCAP) ? (n + (1 << 20)) : n;   // poison on overflow
        base_s[tid] = atomicAdd(&cnt_g[row0 + tid], add);
        n_s[tid] = n;
    }
    __syncthreads();
    for (int s = tid; s < 64 * LCAP; s += 512) {
        const int r = s / LCAP, k2 = s - r * LCAP;
        if (k2 < n_s[r]) {
            const int b = base_s[r] + k2;
            if (b < CAP) cand[(size_t)(row0 + r) * CAP + b] = cbuf[r][k2];
        }
    }
}

// ---------------- K2b: detect + repair bad rows (expected none) ----------------
__global__ void fallback_kernel(const float* __restrict__ feats, const float* __restrict__ sq,
                                int* __restrict__ cand, int* __restrict__ cnt_g) {
    __shared__ float fi_s[DIM];
    __shared__ float keys[NPTS];
    __shared__ float rkey[4];
    __shared__ int   rid[4];
    const int t = threadIdx.x;
    for (int row = blockIdx.x; row < NPTS; row += gridDim.x) {
        const int v = cnt_g[row];
        if (v >= NSLOT && v <= CAP) continue;
        fi_s[t] = feats[(size_t)row * DIM + t];
        __syncthreads();
        const float sqi = sq[row];
        for (int p = 0; p < NPTS / 256; ++p) {
            const int jj = p * 256 + t;
            const float* fj = feats + (size_t)jj * DIM;
            float d = 0.f;
            for (int dq = 0; dq < DIM / 4; ++dq) {
                const float4 b4 = *reinterpret_cast<const float4*>(fj + dq * 4);
                const float4 a4 = *reinterpret_cast<const float4*>(&fi_s[dq * 4]);
                d = fmaf(a4.x, b4.x, fmaf(a4.y, b4.y, fmaf(a4.z, b4.z, fmaf(a4.w, b4.w, d))));
            }
            keys[jj] = sqi + sq[jj] - 2.f * d;
        }
        __syncthreads();
        for (int r = 0; r < 64; ++r) {
            float bk = INFINITY; int bj = 0x7fffffff;
            for (int p = 0; p < NPTS / 256; ++p) {
                const int jj = p * 256 + t;
                const float kv = keys[jj];
                if (kv < bk || (kv == bk && jj < bj)) { bk = kv; bj = jj; }
            }
#pragma unroll
            for (int off = 1; off <= 32; off <<= 1) {
                const float ok = __shfl_xor(bk, off, 64);
                const int   oj = __shfl_xor(bj, off, 64);
                if (ok < bk || (ok == bk && oj < bj)) { bk = ok; bj = oj; }
            }
            if ((t & 63) == 0) { rkey[t >> 6] = bk; rid[t >> 6] = bj; }
            __syncthreads();
            float fk = rkey[0]; int fj2 = rid[0];
#pragma unroll
            for (int q = 1; q < 4; ++q)
                if (rkey[q] < fk || (rkey[q] == fk && rid[q] < fj2)) { fk = rkey[q]; fj2 = rid[q]; }
            if (t == 0) {   // rank-ordered packed key (idx in low 13 bits)
                cand[(size_t)row * CAP + r] = (int)(((uint)(524287 - r) << 13) | (uint)fj2);
                keys[fj2] = INFINITY;
            }
            __syncthreads();
        }
        if (t == 0) cnt_g[row] = 64;
        __syncthreads();
    }
}

// ---------------- K3: preselect top-24 + fp64 refine, one wave/row -> top-17 ----------------
__global__ __launch_bounds__(256) void refine_kernel(
    const float* __restrict__ feats, const int* __restrict__ cand,
    const int* __restrict__ cnt_g, int* __restrict__ fidx, float* __restrict__ fscr) {
    __shared__ float  fi_s[4][DIM];
    __shared__ int    sel_s[4][RSEL];
    __shared__ double kdd_s[4][RSEL];
    __shared__ float  kdot_s[4][RSEL];
    const int w = threadIdx.x >> 6, l = threadIdx.x & 63;
    const int i = blockIdx.x * 4 + w;
    *reinterpret_cast<float4*>(&fi_s[w][l * 4]) =
        *reinterpret_cast<const float4*>(feats + (size_t)i * DIM + l * 4);
    __syncthreads();
    const int nc   = min(cnt_g[i], CAP);
    const int nsel = min(nc, RSEL);
    {   // ---- preselect top-nsel by packed key (order-independent) ----
        const int* crow = cand + (size_t)i * CAP;
        uint pk[4];
#pragma unroll
        for (int p = 0; p < 4; ++p) {
            const int c4 = p * 64 + l;
            pk[p] = (c4 < nc) ? (uint)crow[c4] : 0u;
        }
        for (int r = 0; r < nsel; ++r) {
            uint best = max(max(pk[0], pk[1]), max(pk[2], pk[3]));
#pragma unroll
            for (int off = 1; off <= 32; off <<= 1)
                best = max(best, (uint)__shfl_xor((int)best, off, 64));
            if (l == 0) sel_s[w][r] = (int)(best & 8191u);
#pragma unroll
            for (int p = 0; p < 4; ++p) if (pk[p] == best) pk[p] = 0u;
        }
    }
    // ---- fp64 d2+dot: 8 lanes per candidate, 3 passes of 8 cands ----
    const int ch = l & 7;
#pragma unroll
    for (int pass = 0; pass < 3; ++pass) {
        const int c = pass * 8 + (l >> 3);
        const bool valid = (c < nsel);
        const int j = valid ? sel_s[w][c] : 0;
        const float* fj = feats + (size_t)j * DIM + ch * 32;
        const float* fi = &fi_s[w][ch * 32];
        double dd = 0.0, dot = 0.0;
#pragma unroll
        for (int q = 0; q < 8; ++q) {
            const float4 a4 = *reinterpret_cast<const float4*>(fi + q * 4);
            const float4 b4 = *reinterpret_cast<const float4*>(fj + q * 4);
            const double dx = (double)a4.x - b4.x, dy = (double)a4.y - b4.y;
            const double dz = (double)a4.z - b4.z, dw2 = (double)a4.w - b4.w;
            dd  += dx * dx + dy * dy + dz * dz + dw2 * dw2;
            dot += (double)a4.x * b4.x + (double)a4.y * b4.y +
                   (double)a4.z * b4.z + (double)a4.w * b4.w;
        }
        dd  += __shfl_xor(dd, 1, 64);  dd  += __shfl_xor(dd, 2, 64);  dd  += __shfl_xor(dd, 4, 64);
        dot += __shfl_xor(dot, 1, 64); dot += __shfl_xor(dot, 2, 64); dot += __shfl_xor(dot, 4, 64);
        if (valid && ch == 0) { kdd_s[w][c] = dd; kdot_s[w][c] = (float)dot; }
    }
    // ---- exact top-17 by (d2, idx) ----
    double kk = (l < nsel) ? kdd_s[w][l] : 1e300;
    int    jj = (l < nsel) ? sel_s[w][l] : 0x7fffffff;
    float  ss = (l < nsel) ? kdot_s[w][l] : 0.f;
    for (int r = 0; r < NSLOT; ++r) {
        double bk = kk; int bj = jj; float bs = ss;
#pragma unroll
        for (int off = 1; off <= 32; off <<= 1) {
            const double ok = __shfl_xor(bk, off, 64);
            const int    oj = __shfl_xor(bj, off, 64);
            const float  os = __shfl_xor(bs, off, 64);
            if (ok < bk || (ok == bk && oj < bj)) { bk = ok; bj = oj; bs = os; }
        }
        if (l == 0) { fidx[(size_t)i * NSLOT + r] = bj; fscr[(size_t)i * NSLOT + r] = bs; }
        if (jj == bj) kk = 1e300;
    }
}

// ---------------- K4: mutual mask + sparse softmax + mix + normalize ----------------
__global__ void fcm_out_kernel(const float* __restrict__ feats,
                               const int* __restrict__ knn_idx,
                               const float* __restrict__ knn_scr,
                               float* __restrict__ out) {
    const int w    = threadIdx.x >> 6;
    const int lane = threadIdx.x & 63;
    const int i    = blockIdx.x * 4 + w;

    int jt = -1; float st = 0.f; bool valid = false;
    if (lane < NSLOT) {
        jt = knn_idx[(size_t)i * NSLOT + lane];
        st = knn_scr[(size_t)i * NSLOT + lane];
        if (jt != i) {
            const int* nb = knn_idx + (size_t)jt * NSLOT;
#pragma unroll
            for (int s = 0; s < NSLOT; ++s) valid |= (nb[s] == i);
        }
    }
    float val = valid ? st : -INFINITY;
#pragma unroll
    for (int off = 32; off > 0; off >>= 1) val = fmaxf(val, __shfl_xor(val, off, 64));
    const float m  = fmaxf(1.0f, val);
    const float wt = valid ? expf(st - m) : 0.f;
    float ws = wt;
#pragma unroll
    for (int off = 32; off > 0; off >>= 1) ws += __shfl_xor(ws, off, 64);
    const float wdiag = expf(1.0f - m);
    const float inv   = 1.0f / (ws + wdiag);

    const float4 fi = *reinterpret_cast<const float4*>(feats + (size_t)i * DIM + lane * 4);
    float ax = fi.x * wdiag, ay = fi.y * wdiag, az = fi.z * wdiag, aw = fi.w * wdiag;
    for (int t = 0; t < NSLOT; ++t) {
        const float wtt = __shfl(wt, t, 64);
        const int   jj  = __shfl(jt, t, 64);
        if (wtt > 0.f) {
            const float4 fj = *reinterpret_cast<const float4*>(feats + (size_t)jj * DIM + lane * 4);
            ax = fmaf(wtt, fj.x, ax); ay = fmaf(wtt, fj.y, ay);
            az = fmaf(wtt, fj.z, az); aw = fmaf(wtt, fj.w, aw);
        }
    }
    const float ox = fmaf(ax, inv, fi.x), oy = fmaf(ay, inv, fi.y);
    const float oz = fmaf(az, inv, fi.z), ow = fmaf(aw, inv, fi.w);
    float nn = ox * ox + oy * oy + oz * oz + ow * ow;
#pragma unroll
    for (int off = 32; off > 0; off >>= 1) nn += __shfl_xor(nn, off, 64);
    const float scl = 1.0f / fmaxf(sqrtf(nn), 1e-12f);
    float4 o; o.x = ox * scl; o.y = oy * scl; o.z = oz * scl; o.w = ow * scl;
    *reinterpret_cast<float4*>(out + (size_t)i * DIM + lane * 4) = o;
}

extern "C" void kernel_launch(void* const* d_in, const int* in_sizes, int n_in,
                              void* d_out, int out_size, void* d_ws, size_t ws_size,
                              hipStream_t stream) {
    (void)in_sizes; (void)n_in; (void)out_size; (void)ws_size;
    const float* feats = (const float*)d_in[0];
    float* out = (float*)d_out;
    char* ws = (char*)d_ws;
    size_t off = 0;
    float*  sq    = (float*) (ws + off); off += NPTS * 4;                 // 32 KB
    float*  musig = (float*) (ws + off); off += 128;
    ushort* fb    = (ushort*)(ws + off); off += (size_t)NPTS * DIM * 2;   // 4 MB
    int*    cand  = (int*)   (ws + off); off += (size_t)NPTS * CAP * 4;   // 8 MB
    int*    cnt_g = (int*)   (ws + off); off += NPTS * 4;
    int*    fidx  = (int*)   (ws + off); off += NPTS * NSLOT * 4;
    float*  fscr  = (float*) (ws + off); off += NPTS * NSLOT * 4;

    prep_kernel<<<NPTS / 4, 256, 0, stream>>>(feats, fb, sq, cnt_g);
    stats_kernel<<<1, 1024, 0, stream>>>(sq, musig);
    gemm_select_kernel<<<(NPTS / 64) * 4, 512, 0, stream>>>(fb, sq, musig, cand, cnt_g);
    fallback_kernel<<<64, 256, 0, stream>>>(feats, sq, cand, cnt_g);
    refine_kernel<<<NPTS / 4, 256, 0, stream>>>(feats, cand, cnt_g, fidx, fscr);
    fcm_out_kernel<<<NPTS / 4, 256, 0, stream>>>(feats, fidx, fscr, out);
}

// Round 15
// 184.627 us; speedup vs baseline: 17.3446x; 1.0840x over previous
//
#include <hip/hip_runtime.h>
#include <math.h>

// FCM mutual-kNN attention mixing. N=8192, D=256, K=16.
//   K1 prep:   row sqnorms, zero cnt_g
//   K1b stats: deterministic reduction of sq -> mu/var
//   K1c pack:  feats -> fbp in MFMA-fragment order (cb,kb,lane,8)
//   K2 gemm:   A panel staged as contiguous fbp copy in LDS (conflict-free
//              fragment reads), B streamed from fbp fully coalesced (1KB/frag),
//              barrier-free main loop; threshold select -> packed LDS cbuf.
//   K2b fallback: detect + full-rescan repair of bad rows (expected none)
//   K3 refine: top-24 preselect by packed key -> fp64 d2+dot -> exact top-17
//   K4 out:    mutual mask + sparse softmax + mix + normalize
#define NPTS 8192
#define DIM  256
#define NSLOT 17
#define CAP  256
#define LCAP 48
#define RSEL 24
#define ZTH  (-2.45f)
typedef unsigned int uint;
typedef unsigned short ushort;
typedef __attribute__((ext_vector_type(8))) short bf16x8;
typedef __attribute__((ext_vector_type(4))) float f32x4;

__device__ __forceinline__ ushort f2bf(float f) {
    uint x = __float_as_uint(f);
    return (ushort)((x + 0x7fffu + ((x >> 16) & 1u)) >> 16);
}

// ---------------- K1: sqnorms + cnt_g=0 ----------------
__global__ void prep_kernel(const float* __restrict__ feats,
                            float* __restrict__ sq, int* __restrict__ cnt_g) {
    const int row  = blockIdx.x * 4 + (threadIdx.x >> 6);
    const int lane = threadIdx.x & 63;
    const float4 v = *reinterpret_cast<const float4*>(feats + (size_t)row * DIM + lane * 4);
    float p = v.x * v.x + v.y * v.y + v.z * v.z + v.w * v.w;
#pragma unroll
    for (int off = 32; off > 0; off >>= 1) p += __shfl_down(p, off, 64);
    if (lane == 0) { sq[row] = p; cnt_g[row] = 0; }
}

// ---------------- K1b: deterministic stats (mu, var) ----------------
__global__ void stats_kernel(const float* __restrict__ sq, float* __restrict__ musig) {
    __shared__ double s0s[16], s1s[16];
    const int t = threadIdx.x, lane = t & 63, w = t >> 6;
    double s0 = 0.0, s1 = 0.0;
    for (int r = t; r < NPTS; r += 1024) {
        const double v = (double)sq[r];
        s0 += v; s1 += v * v;
    }
#pragma unroll
    for (int off = 32; off > 0; off >>= 1) {
        s0 += __shfl_down(s0, off, 64);
        s1 += __shfl_down(s1, off, 64);
    }
    if (lane == 0) { s0s[w] = s0; s1s[w] = s1; }
    __syncthreads();
    if (t == 0) {
        double a0 = 0.0, a1 = 0.0;
#pragma unroll
        for (int q = 0; q < 16; ++q) { a0 += s0s[q]; a1 += s1s[q]; }
        const double mu = a0 / NPTS;
        const double var = a1 / NPTS - mu * mu;
        musig[0] = (float)mu;
        musig[1] = (float)fmax(var, 1.0);
    }
}

// ---------------- K1c: pack feats -> fragment-ordered bf16 ----------------
// fbp[((cb*8+kb)*64 + l)*8 + q] = bf16(F[cb*16 + (l&15)][kb*32 + (l>>4)*8 + q])
__global__ void pack_kernel(const float* __restrict__ feats, ushort* __restrict__ fbp) {
    const int cb = (blockIdx.x * 256 + threadIdx.x) >> 6;   // global wave id
    const int l  = threadIdx.x & 63;
    const int l15 = l & 15, lg = l >> 4;
    const float* src = feats + (size_t)(cb * 16 + l15) * DIM + lg * 8;
    ushort* dst = fbp + (size_t)cb * 4096 + l * 8;
#pragma unroll
    for (int kb = 0; kb < 8; ++kb) {
        const float4 v0 = *reinterpret_cast<const float4*>(src + kb * 32);
        const float4 v1 = *reinterpret_cast<const float4*>(src + kb * 32 + 4);
        bf16x8 bv;
        bv[0] = (short)f2bf(v0.x); bv[1] = (short)f2bf(v0.y);
        bv[2] = (short)f2bf(v0.z); bv[3] = (short)f2bf(v0.w);
        bv[4] = (short)f2bf(v1.x); bv[5] = (short)f2bf(v1.y);
        bv[6] = (short)f2bf(v1.z); bv[7] = (short)f2bf(v1.w);
        *reinterpret_cast<bf16x8*>(dst + kb * 512) = bv;
    }
}

// ---------------- K2: barrier-free MFMA GEMM + fused threshold select ----------------
// 512 thr = 8 waves. Block: 64 rows x 2048-col quarter (quarter pinned per XCD).
// A: 32KB contiguous copy of fbp -> LDS; fragment reads lane-consecutive (0-conflict).
// B: coalesced 1KB fragment loads from fbp, depth-1 reg ping-pong, no barriers.
__global__ __launch_bounds__(512, 2) void gemm_select_kernel(
    const ushort* __restrict__ fbp, const float* __restrict__ sq,
    const float* __restrict__ musig, int* __restrict__ cand, int* __restrict__ cnt_g) {
    __shared__ ushort As[16384];         // 32 KB fragment-ordered A panel
    __shared__ int    cbuf[64][LCAP];    // 12 KB packed (keyq<<13)|idx
    __shared__ float  Ts[64], sqi_s[64];
    __shared__ int    cnt[64];
    __shared__ int    base_s[64], n_s[64];

    const int tid = threadIdx.x;
    const int w   = tid >> 6;
    const int l   = tid & 63;
    const int l15 = l & 15, lg = l >> 4;
    const int rowblk = (blockIdx.x >> 3) * 2 + (blockIdx.x & 1);
    const int row0   = rowblk * 64;
    const int Jbase  = ((blockIdx.x & 7) >> 1) * 2048;

    if (tid < 64) {
        const float mu  = musig[0];
        const float var = musig[1];
        const float qi  = sq[row0 + tid];
        sqi_s[tid] = qi;
        Ts[tid]    = qi + mu + ZTH * sqrtf(var + 4.f * qi);
        cnt[tid]   = 0;
    }
    {   // stage A panel: straight 32KB copy (4 colblks of fbp)
        const ushort* src = fbp + (size_t)(row0 >> 4) * 4096;
#pragma unroll
        for (int s = 0; s < 4; ++s) {
            const int idx = tid + s * 512;
            *reinterpret_cast<bf16x8*>(As + idx * 8) =
                *reinterpret_cast<const bf16x8*>(src + (size_t)idx * 8);
        }
    }
    __syncthreads();                     // the ONLY barrier before the merge

    const int gcol = w * 32;
    // B fragment base: colblk cbw = (Jbase>>4) + tile*16 + w*2 + cf, slot ks.
    const ushort* bp = fbp + (size_t)((Jbase >> 4) + w * 2) * 4096 + l * 8;

    bf16x8 bb[2][2];
#pragma unroll
    for (int cf = 0; cf < 2; ++cf)
        bb[0][cf] = *reinterpret_cast<const bf16x8*>(bp + cf * 4096);

    for (int tile = 0; tile < 8; ++tile) {
        f32x4 acc[4][2];
#pragma unroll
        for (int mf = 0; mf < 4; ++mf) {
            acc[mf][0] = (f32x4){0.f, 0.f, 0.f, 0.f};
            acc[mf][1] = (f32x4){0.f, 0.f, 0.f, 0.f};
        }
#pragma unroll
        for (int ks = 0; ks < 8; ++ks) {
            const int cur = ks & 1;
            if (tile < 7 || ks < 7) {    // prefetch next fragment pair
                const int ntile = (ks == 7) ? tile + 1 : tile;
                const int nks   = (ks == 7) ? 0 : ks + 1;
#pragma unroll
                for (int cf = 0; cf < 2; ++cf)
                    bb[cur ^ 1][cf] = *reinterpret_cast<const bf16x8*>(
                        bp + (size_t)ntile * 65536 + cf * 4096 + nks * 512);
            }
            bf16x8 af[4];
#pragma unroll
            for (int mf = 0; mf < 4; ++mf)
                af[mf] = *reinterpret_cast<const bf16x8*>(
                    As + ((mf * 8 + ks) * 64 + l) * 8);
#pragma unroll
            for (int mf = 0; mf < 4; ++mf) {
                acc[mf][0] = __builtin_amdgcn_mfma_f32_16x16x32_bf16(af[mf], bb[cur][0], acc[mf][0], 0, 0, 0);
                acc[mf][1] = __builtin_amdgcn_mfma_f32_16x16x32_bf16(af[mf], bb[cur][1], acc[mf][1], 0, 0, 0);
            }
        }
        // ---- per-tile epilogue: threshold select, packed into LDS cbuf ----
        const int Jt = Jbase + tile * 256;
        float sqc[2];
#pragma unroll
        for (int cf = 0; cf < 2; ++cf) sqc[cf] = sq[Jt + gcol + cf * 16 + l15];
#pragma unroll
        for (int mf = 0; mf < 4; ++mf)
#pragma unroll
            for (int cf = 0; cf < 2; ++cf)
#pragma unroll
                for (int r = 0; r < 4; ++r) {
                    const int row = mf * 16 + lg * 4 + r;
                    const float tt = Ts[row];
                    const float key = sqi_s[row] + sqc[cf] - 2.f * acc[mf][cf][r];
                    if (key < tt) {
                        const int kq2 = min((int)((tt - key) * 4096.f), 524287);
                        const uint val = ((uint)max(kq2, 0) << 13) |
                                         (uint)(Jt + gcol + cf * 16 + l15);
                        const int pos = atomicAdd(&cnt[row], 1);
                        if (pos < LCAP) cbuf[row][pos] = (int)val;
                    }
                }
    }
    __syncthreads();
    if (tid < 64) {
        const int local = cnt[tid];
        const int n = min(local, LCAP);
        const int add = (local > LCAP) ? (n + (1 << 20)) : n;   // poison on overflow
        base_s[tid] = atomicAdd(&cnt_g[row0 + tid], add);
        n_s[tid] = n;
    }
    __syncthreads();
    for (int s = tid; s < 64 * LCAP; s += 512) {
        const int r = s / LCAP, k2 = s - r * LCAP;
        if (k2 < n_s[r]) {
            const int b = base_s[r] + k2;
            if (b < CAP) cand[(size_t)(row0 + r) * CAP + b] = cbuf[r][k2];
        }
    }
}

// ---------------- K2b: detect + repair bad rows (expected none) ----------------
__global__ void fallback_kernel(const float* __restrict__ feats, const float* __restrict__ sq,
                                int* __restrict__ cand, int* __restrict__ cnt_g) {
    __shared__ float fi_s[DIM];
    __shared__ float keys[NPTS];
    __shared__ float rkey[4];
    __shared__ int   rid[4];
    const int t = threadIdx.x;
    for (int row = blockIdx.x; row < NPTS; row += gridDim.x) {
        const int v = cnt_g[row];
        if (v >= NSLOT && v <= CAP) continue;
        fi_s[t] = feats[(size_t)row * DIM + t];
        __syncthreads();
        const float sqi = sq[row];
        for (int p = 0; p < NPTS / 256; ++p) {
            const int jj = p * 256 + t;
            const float* fj = feats + (size_t)jj * DIM;
            float d = 0.f;
            for (int dq = 0; dq < DIM / 4; ++dq) {
                const float4 b4 = *reinterpret_cast<const float4*>(fj + dq * 4);
                const float4 a4 = *reinterpret_cast<const float4*>(&fi_s[dq * 4]);
                d = fmaf(a4.x, b4.x, fmaf(a4.y, b4.y, fmaf(a4.z, b4.z, fmaf(a4.w, b4.w, d))));
            }
            keys[jj] = sqi + sq[jj] - 2.f * d;
        }
        __syncthreads();
        for (int r = 0; r < 64; ++r) {
            float bk = INFINITY; int bj = 0x7fffffff;
            for (int p = 0; p < NPTS / 256; ++p) {
                const int jj = p * 256 + t;
                const float kv = keys[jj];
                if (kv < bk || (kv == bk && jj < bj)) { bk = kv; bj = jj; }
            }
#pragma unroll
            for (int off = 1; off <= 32; off <<= 1) {
                const float ok = __shfl_xor(bk, off, 64);
                const int   oj = __shfl_xor(bj, off, 64);
                if (ok < bk || (ok == bk && oj < bj)) { bk = ok; bj = oj; }
            }
            if ((t & 63) == 0) { rkey[t >> 6] = bk; rid[t >> 6] = bj; }
            __syncthreads();
            float fk = rkey[0]; int fj2 = rid[0];
#pragma unroll
            for (int q = 1; q < 4; ++q)
                if (rkey[q] < fk || (rkey[q] == fk && rid[q] < fj2)) { fk = rkey[q]; fj2 = rid[q]; }
            if (t == 0) {   // rank-ordered packed key (idx in low 13 bits)
                cand[(size_t)row * CAP + r] = (int)(((uint)(524287 - r) << 13) | (uint)fj2);
                keys[fj2] = INFINITY;
            }
            __syncthreads();
        }
        if (t == 0) cnt_g[row] = 64;
        __syncthreads();
    }
}

// ---------------- K3: preselect top-24 + fp64 refine, one wave/row -> top-17 ----------------
__global__ __launch_bounds__(256) void refine_kernel(
    const float* __restrict__ feats, const int* __restrict__ cand,
    const int* __restrict__ cnt_g, int* __restrict__ fidx, float* __restrict__ fscr) {
    __shared__ float  fi_s[4][DIM];
    __shared__ int    sel_s[4][RSEL];
    __shared__ double kdd_s[4][RSEL];
    __shared__ float  kdot_s[4][RSEL];
    const int w = threadIdx.x >> 6, l = threadIdx.x & 63;
    const int i = blockIdx.x * 4 + w;
    *reinterpret_cast<float4*>(&fi_s[w][l * 4]) =
        *reinterpret_cast<const float4*>(feats + (size_t)i * DIM + l * 4);
    __syncthreads();
    const int nc   = min(cnt_g[i], CAP);
    const int nsel = min(nc, RSEL);
    {   // preselect top-nsel by packed key (order-independent)
        const int* crow = cand + (size_t)i * CAP;
        uint pk[4];
#pragma unroll
        for (int p = 0; p < 4; ++p) {
            const int c4 = p * 64 + l;
            pk[p] = (c4 < nc) ? (uint)crow[c4] : 0u;
        }
        for (int r = 0; r < nsel; ++r) {
            uint best = max(max(pk[0], pk[1]), max(pk[2], pk[3]));
#pragma unroll
            for (int off = 1; off <= 32; off <<= 1)
                best = max(best, (uint)__shfl_xor((int)best, off, 64));
            if (l == 0) sel_s[w][r] = (int)(best & 8191u);
#pragma unroll
            for (int p = 0; p < 4; ++p) if (pk[p] == best) pk[p] = 0u;
        }
    }
    const int ch = l & 7;                // 8 lanes/cand, 3 passes
#pragma unroll
    for (int pass = 0; pass < 3; ++pass) {
        const int c = pass * 8 + (l >> 3);
        const bool valid = (c < nsel);
        const int j = valid ? sel_s[w][c] : 0;
        const float* fj = feats + (size_t)j * DIM + ch * 32;
        const float* fi = &fi_s[w][ch * 32];
        double dd = 0.0, dot = 0.0;
#pragma unroll
        for (int q = 0; q < 8; ++q) {
            const float4 a4 = *reinterpret_cast<const float4*>(fi + q * 4);
            const float4 b4 = *reinterpret_cast<const float4*>(fj + q * 4);
            const double dx = (double)a4.x - b4.x, dy = (double)a4.y - b4.y;
            const double dz = (double)a4.z - b4.z, dw2 = (double)a4.w - b4.w;
            dd  += dx * dx + dy * dy + dz * dz + dw2 * dw2;
            dot += (double)a4.x * b4.x + (double)a4.y * b4.y +
                   (double)a4.z * b4.z + (double)a4.w * b4.w;
        }
        dd  += __shfl_xor(dd, 1, 64);  dd  += __shfl_xor(dd, 2, 64);  dd  += __shfl_xor(dd, 4, 64);
        dot += __shfl_xor(dot, 1, 64); dot += __shfl_xor(dot, 2, 64); dot += __shfl_xor(dot, 4, 64);
        if (valid && ch == 0) { kdd_s[w][c] = dd; kdot_s[w][c] = (float)dot; }
    }
    double kk = (l < nsel) ? kdd_s[w][l] : 1e300;
    int    jj = (l < nsel) ? sel_s[w][l] : 0x7fffffff;
    float  ss = (l < nsel) ? kdot_s[w][l] : 0.f;
    for (int r = 0; r < NSLOT; ++r) {
        double bk = kk; int bj = jj; float bs = ss;
#pragma unroll
        for (int off = 1; off <= 32; off <<= 1) {
            const double ok = __shfl_xor(bk, off, 64);
            const int    oj = __shfl_xor(bj, off, 64);
            const float  os = __shfl_xor(bs, off, 64);
            if (ok < bk || (ok == bk && oj < bj)) { bk = ok; bj = oj; bs = os; }
        }
        if (l == 0) { fidx[(size_t)i * NSLOT + r] = bj; fscr[(size_t)i * NSLOT + r] = bs; }
        if (jj == bj) kk = 1e300;
    }
}

// ---------------- K4: mutual mask + sparse softmax + mix + normalize ----------------
__global__ void fcm_out_kernel(const float* __restrict__ feats,
                               const int* __restrict__ knn_idx,
                               const float* __restrict__ knn_scr,
                               float* __restrict__ out) {
    const int w    = threadIdx.x >> 6;
    const int lane = threadIdx.x & 63;
    const int i    = blockIdx.x * 4 + w;

    int jt = -1; float st = 0.f; bool valid = false;
    if (lane < NSLOT) {
        jt = knn_idx[(size_t)i * NSLOT + lane];
        st = knn_scr[(size_t)i * NSLOT + lane];
        if (jt != i) {
            const int* nb = knn_idx + (size_t)jt * NSLOT;
#pragma unroll
            for (int s = 0; s < NSLOT; ++s) valid |= (nb[s] == i);
        }
    }
    float val = valid ? st : -INFINITY;
#pragma unroll
    for (int off = 32; off > 0; off >>= 1) val = fmaxf(val, __shfl_xor(val, off, 64));
    const float m  = fmaxf(1.0f, val);
    const float wt = valid ? expf(st - m) : 0.f;
    float ws = wt;
#pragma unroll
    for (int off = 32; off > 0; off >>= 1) ws += __shfl_xor(ws, off, 64);
    const float wdiag = expf(1.0f - m);
    const float inv   = 1.0f / (ws + wdiag);

    const float4 fi = *reinterpret_cast<const float4*>(feats + (size_t)i * DIM + lane * 4);
    float ax = fi.x * wdiag, ay = fi.y * wdiag, az = fi.z * wdiag, aw = fi.w * wdiag;
    for (int t = 0; t < NSLOT; ++t) {
        const float wtt = __shfl(wt, t, 64);
        const int   jj  = __shfl(jt, t, 64);
        if (wtt > 0.f) {
            const float4 fj = *reinterpret_cast<const float4*>(feats + (size_t)jj * DIM + lane * 4);
            ax = fmaf(wtt, fj.x, ax); ay = fmaf(wtt, fj.y, ay);
            az = fmaf(wtt, fj.z, az); aw = fmaf(wtt, fj.w, aw);
        }
    }
    const float ox = fmaf(ax, inv, fi.x), oy = fmaf(ay, inv, fi.y);
    const float oz = fmaf(az, inv, fi.z), ow = fmaf(aw, inv, fi.w);
    float nn = ox * ox + oy * oy + oz * oz + ow * ow;
#pragma unroll
    for (int off = 32; off > 0; off >>= 1) nn += __shfl_xor(nn, off, 64);
    const float scl = 1.0f / fmaxf(sqrtf(nn), 1e-12f);
    float4 o; o.x = ox * scl; o.y = oy * scl; o.z = oz * scl; o.w = ow * scl;
    *reinterpret_cast<float4*>(out + (size_t)i * DIM + lane * 4) = o;
}

extern "C" void kernel_launch(void* const* d_in, const int* in_sizes, int n_in,
                              void* d_out, int out_size, void* d_ws, size_t ws_size,
                              hipStream_t stream) {
    (void)in_sizes; (void)n_in; (void)out_size; (void)ws_size;
    const float* feats = (const float*)d_in[0];
    float* out = (float*)d_out;
    char* ws = (char*)d_ws;
    size_t off = 0;
    float*  sq    = (float*) (ws + off); off += NPTS * 4;                 // 32 KB
    float*  musig = (float*) (ws + off); off += 128;
    ushort* fbp   = (ushort*)(ws + off); off += (size_t)NPTS * DIM * 2;   // 4 MB packed
    int*    cand  = (int*)   (ws + off); off += (size_t)NPTS * CAP * 4;   // 8 MB
    int*    cnt_g = (int*)   (ws + off); off += NPTS * 4;
    int*    fidx  = (int*)   (ws + off); off += NPTS * NSLOT * 4;
    float*  fscr  = (float*) (ws + off); off += NPTS * NSLOT * 4;

    prep_kernel<<<NPTS / 4, 256, 0, stream>>>(feats, sq, cnt_g);
    stats_kernel<<<1, 1024, 0, stream>>>(sq, musig);
    pack_kernel<<<NPTS / 64, 256, 0, stream>>>(feats, fbp);
    gemm_select_kernel<<<(NPTS / 64) * 4, 512, 0, stream>>>(fbp, sq, musig, cand, cnt_g);
    fallback_kernel<<<64, 256, 0, stream>>>(feats, sq, cand, cnt_g);
    refine_kernel<<<NPTS / 4, 256, 0, stream>>>(feats, cand, cnt_g, fidx, fscr);
    fcm_out_kernel<<<NPTS / 4, 256, 0, stream>>>(feats, fidx, fscr, out);
}

// Round 16
// 166.503 us; speedup vs baseline: 19.2326x; 1.1089x over previous
//
#include <hip/hip_runtime.h>
#include <math.h>

// FCM mutual-kNN attention mixing. N=8192, D=256, K=16.
//   K1 pack:   feats -> fbp fragment order + row sqnorms + zero cnt_g (fused)
//   K1b stats: deterministic reduction of sq -> mu/var
//   K2 gemm:   A panel contiguous in LDS, B coalesced fragment stream,
//              barrier-free; threshold select -> packed LDS cbuf -> merge.
//   K2b fallback: detect + full-rescan repair of bad rows (expected none)
//   K3 refine: 1 cand/lane fp64 d2+dot -> u64 composite key -> ballot-bisection
//              top-17 set (no cross-lane shuffles). One wave per row.
//   K4 out:    mutual mask + sparse softmax + mix + normalize
#define NPTS 8192
#define DIM  256
#define NSLOT 17
#define CAP  256
#define LCAP 48
#define ZTH  (-2.45f)
typedef unsigned int uint;
typedef unsigned short ushort;
typedef unsigned long long ull;
typedef __attribute__((ext_vector_type(8))) short bf16x8;
typedef __attribute__((ext_vector_type(4))) float f32x4;

__device__ __forceinline__ ushort f2bf(float f) {
    uint x = __float_as_uint(f);
    return (ushort)((x + 0x7fffu + ((x >> 16) & 1u)) >> 16);
}

// ---------------- K1: pack feats -> fragment order + sqnorms + cnt_g=0 ----------------
// fbp[((cb*8+kb)*64 + l)*8 + q] = bf16(F[cb*16 + (l&15)][kb*32 + (l>>4)*8 + q])
__global__ void pack_kernel(const float* __restrict__ feats, ushort* __restrict__ fbp,
                            float* __restrict__ sq, int* __restrict__ cnt_g) {
    const int cb = (blockIdx.x * 256 + threadIdx.x) >> 6;   // global wave id
    const int l  = threadIdx.x & 63;
    const int l15 = l & 15, lg = l >> 4;
    const float* src = feats + (size_t)(cb * 16 + l15) * DIM + lg * 8;
    ushort* dst = fbp + (size_t)cb * 4096 + l * 8;
    float p = 0.f;
#pragma unroll
    for (int kb = 0; kb < 8; ++kb) {
        const float4 v0 = *reinterpret_cast<const float4*>(src + kb * 32);
        const float4 v1 = *reinterpret_cast<const float4*>(src + kb * 32 + 4);
        p += v0.x * v0.x + v0.y * v0.y + v0.z * v0.z + v0.w * v0.w
           + v1.x * v1.x + v1.y * v1.y + v1.z * v1.z + v1.w * v1.w;
        bf16x8 bv;
        bv[0] = (short)f2bf(v0.x); bv[1] = (short)f2bf(v0.y);
        bv[2] = (short)f2bf(v0.z); bv[3] = (short)f2bf(v0.w);
        bv[4] = (short)f2bf(v1.x); bv[5] = (short)f2bf(v1.y);
        bv[6] = (short)f2bf(v1.z); bv[7] = (short)f2bf(v1.w);
        *reinterpret_cast<bf16x8*>(dst + kb * 512) = bv;
    }
    p += __shfl_xor(p, 16, 64);
    p += __shfl_xor(p, 32, 64);
    if (lg == 0) { sq[cb * 16 + l15] = p; cnt_g[cb * 16 + l15] = 0; }
}

// ---------------- K1b: deterministic stats (mu, var) ----------------
__global__ void stats_kernel(const float* __restrict__ sq, float* __restrict__ musig) {
    __shared__ double s0s[16], s1s[16];
    const int t = threadIdx.x, lane = t & 63, w = t >> 6;
    double s0 = 0.0, s1 = 0.0;
    for (int r = t; r < NPTS; r += 1024) {
        const double v = (double)sq[r];
        s0 += v; s1 += v * v;
    }
#pragma unroll
    for (int off = 32; off > 0; off >>= 1) {
        s0 += __shfl_down(s0, off, 64);
        s1 += __shfl_down(s1, off, 64);
    }
    if (lane == 0) { s0s[w] = s0; s1s[w] = s1; }
    __syncthreads();
    if (t == 0) {
        double a0 = 0.0, a1 = 0.0;
#pragma unroll
        for (int q = 0; q < 16; ++q) { a0 += s0s[q]; a1 += s1s[q]; }
        const double mu = a0 / NPTS;
        const double var = a1 / NPTS - mu * mu;
        musig[0] = (float)mu;
        musig[1] = (float)fmax(var, 1.0);
    }
}

// ---------------- K2: barrier-free MFMA GEMM + fused threshold select ----------------
// [round-15 verbatim] 512 thr = 8 waves. Block: 64 rows x 2048-col quarter.
__global__ __launch_bounds__(512, 2) void gemm_select_kernel(
    const ushort* __restrict__ fbp, const float* __restrict__ sq,
    const float* __restrict__ musig, int* __restrict__ cand, int* __restrict__ cnt_g) {
    __shared__ ushort As[16384];         // 32 KB fragment-ordered A panel
    __shared__ int    cbuf[64][LCAP];    // 12 KB packed (keyq<<13)|idx
    __shared__ float  Ts[64], sqi_s[64];
    __shared__ int    cnt[64];
    __shared__ int    base_s[64], n_s[64];

    const int tid = threadIdx.x;
    const int w   = tid >> 6;
    const int l   = tid & 63;
    const int l15 = l & 15, lg = l >> 4;
    const int rowblk = (blockIdx.x >> 3) * 2 + (blockIdx.x & 1);
    const int row0   = rowblk * 64;
    const int Jbase  = ((blockIdx.x & 7) >> 1) * 2048;

    if (tid < 64) {
        const float mu  = musig[0];
        const float var = musig[1];
        const float qi  = sq[row0 + tid];
        sqi_s[tid] = qi;
        Ts[tid]    = qi + mu + ZTH * sqrtf(var + 4.f * qi);
        cnt[tid]   = 0;
    }
    {   // stage A panel: straight 32KB copy (4 colblks of fbp)
        const ushort* src = fbp + (size_t)(row0 >> 4) * 4096;
#pragma unroll
        for (int s = 0; s < 4; ++s) {
            const int idx = tid + s * 512;
            *reinterpret_cast<bf16x8*>(As + idx * 8) =
                *reinterpret_cast<const bf16x8*>(src + (size_t)idx * 8);
        }
    }
    __syncthreads();                     // the ONLY barrier before the merge

    const int gcol = w * 32;
    const ushort* bp = fbp + (size_t)((Jbase >> 4) + w * 2) * 4096 + l * 8;

    bf16x8 bb[2][2];
#pragma unroll
    for (int cf = 0; cf < 2; ++cf)
        bb[0][cf] = *reinterpret_cast<const bf16x8*>(bp + cf * 4096);

    for (int tile = 0; tile < 8; ++tile) {
        f32x4 acc[4][2];
#pragma unroll
        for (int mf = 0; mf < 4; ++mf) {
            acc[mf][0] = (f32x4){0.f, 0.f, 0.f, 0.f};
            acc[mf][1] = (f32x4){0.f, 0.f, 0.f, 0.f};
        }
#pragma unroll
        for (int ks = 0; ks < 8; ++ks) {
            const int cur = ks & 1;
            if (tile < 7 || ks < 7) {    // prefetch next fragment pair
                const int ntile = (ks == 7) ? tile + 1 : tile;
                const int nks   = (ks == 7) ? 0 : ks + 1;
#pragma unroll
                for (int cf = 0; cf < 2; ++cf)
                    bb[cur ^ 1][cf] = *reinterpret_cast<const bf16x8*>(
                        bp + (size_t)ntile * 65536 + cf * 4096 + nks * 512);
            }
            bf16x8 af[4];
#pragma unroll
            for (int mf = 0; mf < 4; ++mf)
                af[mf] = *reinterpret_cast<const bf16x8*>(
                    As + ((mf * 8 + ks) * 64 + l) * 8);
#pragma unroll
            for (int mf = 0; mf < 4; ++mf) {
                acc[mf][0] = __builtin_amdgcn_mfma_f32_16x16x32_bf16(af[mf], bb[cur][0], acc[mf][0], 0, 0, 0);
                acc[mf][1] = __builtin_amdgcn_mfma_f32_16x16x32_bf16(af[mf], bb[cur][1], acc[mf][1], 0, 0, 0);
            }
        }
        // ---- per-tile epilogue: threshold select, packed into LDS cbuf ----
        const int Jt = Jbase + tile * 256;
        float sqc[2];
#pragma unroll
        for (int cf = 0; cf < 2; ++cf) sqc[cf] = sq[Jt + gcol + cf * 16 + l15];
#pragma unroll
        for (int mf = 0; mf < 4; ++mf)
#pragma unroll
            for (int cf = 0; cf < 2; ++cf)
#pragma unroll
                for (int r = 0; r < 4; ++r) {
                    const int row = mf * 16 + lg * 4 + r;
                    const float tt = Ts[row];
                    const float key = sqi_s[row] + sqc[cf] - 2.f * acc[mf][cf][r];
                    if (key < tt) {
                        const int kq2 = min((int)((tt - key) * 4096.f), 524287);
                        const uint val = ((uint)max(kq2, 0) << 13) |
                                         (uint)(Jt + gcol + cf * 16 + l15);
                        const int pos = atomicAdd(&cnt[row], 1);
                        if (pos < LCAP) cbuf[row][pos] = (int)val;
                    }
                }
    }
    __syncthreads();
    if (tid < 64) {
        const int local = cnt[tid];
        const int n = min(local, LCAP);
        const int add = (local > LCAP) ? (n + (1 << 20)) : n;   // poison on overflow
        base_s[tid] = atomicAdd(&cnt_g[row0 + tid], add);
        n_s[tid] = n;
    }
    __syncthreads();
    for (int s = tid; s < 64 * LCAP; s += 512) {
        const int r = s / LCAP, k2 = s - r * LCAP;
        if (k2 < n_s[r]) {
            const int b = base_s[r] + k2;
            if (b < CAP) cand[(size_t)(row0 + r) * CAP + b] = cbuf[r][k2];
        }
    }
}

// ---------------- K2b: detect + repair bad rows (expected none) ----------------
__global__ void fallback_kernel(const float* __restrict__ feats, const float* __restrict__ sq,
                                int* __restrict__ cand, int* __restrict__ cnt_g) {
    __shared__ float fi_s[DIM];
    __shared__ float keys[NPTS];
    __shared__ float rkey[4];
    __shared__ int   rid[4];
    const int t = threadIdx.x;
    for (int row = blockIdx.x; row < NPTS; row += gridDim.x) {
        const int v = cnt_g[row];
        if (v >= NSLOT && v <= CAP) continue;
        fi_s[t] = feats[(size_t)row * DIM + t];
        __syncthreads();
        const float sqi = sq[row];
        for (int p = 0; p < NPTS / 256; ++p) {
            const int jj = p * 256 + t;
            const float* fj = feats + (size_t)jj * DIM;
            float d = 0.f;
            for (int dq = 0; dq < DIM / 4; ++dq) {
                const float4 b4 = *reinterpret_cast<const float4*>(fj + dq * 4);
                const float4 a4 = *reinterpret_cast<const float4*>(&fi_s[dq * 4]);
                d = fmaf(a4.x, b4.x, fmaf(a4.y, b4.y, fmaf(a4.z, b4.z, fmaf(a4.w, b4.w, d))));
            }
            keys[jj] = sqi + sq[jj] - 2.f * d;
        }
        __syncthreads();
        for (int r = 0; r < 64; ++r) {
            float bk = INFINITY; int bj = 0x7fffffff;
            for (int p = 0; p < NPTS / 256; ++p) {
                const int jj = p * 256 + t;
                const float kv = keys[jj];
                if (kv < bk || (kv == bk && jj < bj)) { bk = kv; bj = jj; }
            }
#pragma unroll
            for (int off = 1; off <= 32; off <<= 1) {
                const float ok = __shfl_xor(bk, off, 64);
                const int   oj = __shfl_xor(bj, off, 64);
                if (ok < bk || (ok == bk && oj < bj)) { bk = ok; bj = oj; }
            }
            if ((t & 63) == 0) { rkey[t >> 6] = bk; rid[t >> 6] = bj; }
            __syncthreads();
            float fk = rkey[0]; int fj2 = rid[0];
#pragma unroll
            for (int q = 1; q < 4; ++q)
                if (rkey[q] < fk || (rkey[q] == fk && rid[q] < fj2)) { fk = rkey[q]; fj2 = rid[q]; }
            if (t == 0) {   // idx in low 13 bits (refine recomputes fp64 from idx)
                cand[(size_t)row * CAP + r] = (int)(((uint)(524287 - r) << 13) | (uint)fj2);
                keys[fj2] = INFINITY;
            }
            __syncthreads();
        }
        if (t == 0) cnt_g[row] = 64;
        __syncthreads();
    }
}

// ---------------- K3: fp64 refine via composite-key ballot bisection ----------------
// One wave/row; 1 cand/lane, <=4 static batches. fi_s reads are wave-uniform
// (broadcast, conflict-free). Top-17 SET extracted with zero cross-lane shuffles.
__global__ __launch_bounds__(256) void refine_kernel(
    const float* __restrict__ feats, const int* __restrict__ cand,
    const int* __restrict__ cnt_g, int* __restrict__ fidx, float* __restrict__ fscr) {
    __shared__ float fi_s[4][DIM];
    const int w = threadIdx.x >> 6, l = threadIdx.x & 63;
    const int i = blockIdx.x * 4 + w;
    *reinterpret_cast<float4*>(&fi_s[w][l * 4]) =
        *reinterpret_cast<const float4*>(feats + (size_t)i * DIM + l * 4);
    __syncthreads();                     // only barrier; waves diverge after
    const int nc = min(cnt_g[i], CAP);
    const int* crow = cand + (size_t)i * CAP;
    ull   key[4];
    float dotf[4];
    int   jidx[4];
#pragma unroll
    for (int b = 0; b < 4; ++b) { key[b] = ~0ULL; dotf[b] = 0.f; jidx[b] = 0; }
#pragma unroll
    for (int b = 0; b < 4; ++b) {
        if (b * 64 >= nc) break;         // wave-uniform
        const int c = b * 64 + l;
        const bool act = (c < nc);
        const int j = act ? (crow[c] & 8191) : i;
        const float* fj = feats + (size_t)j * DIM;
        double dd0 = 0.0, dd1 = 0.0, dot0 = 0.0, dot1 = 0.0;
#pragma unroll 8
        for (int dq = 0; dq < DIM / 8; ++dq) {
            const float4 a0 = *reinterpret_cast<const float4*>(&fi_s[w][dq * 8]);
            const float4 a1 = *reinterpret_cast<const float4*>(&fi_s[w][dq * 8 + 4]);
            const float4 b0 = *reinterpret_cast<const float4*>(fj + dq * 8);
            const float4 b1 = *reinterpret_cast<const float4*>(fj + dq * 8 + 4);
            {
                const double dx = (double)a0.x - b0.x, dy = (double)a0.y - b0.y;
                const double dz = (double)a0.z - b0.z, dw2 = (double)a0.w - b0.w;
                dd0  += dx * dx + dy * dy + dz * dz + dw2 * dw2;
                dot0 += (double)a0.x * b0.x + (double)a0.y * b0.y +
                        (double)a0.z * b0.z + (double)a0.w * b0.w;
            }
            {
                const double dx = (double)a1.x - b1.x, dy = (double)a1.y - b1.y;
                const double dz = (double)a1.z - b1.z, dw2 = (double)a1.w - b1.w;
                dd1  += dx * dx + dy * dy + dz * dz + dw2 * dw2;
                dot1 += (double)a1.x * b1.x + (double)a1.y * b1.y +
                        (double)a1.z * b1.z + (double)a1.w * b1.w;
            }
        }
        const double dd = dd0 + dd1;
        // composite sortable key: positive-double bits, low 13 mantissa bits -> idx
        key[b]  = act ? ((ull)(__double_as_longlong(dd) & ~8191LL) | (ull)(uint)j) : ~0ULL;
        dotf[b] = (float)(dot0 + dot1);
        jidx[b] = j;
    }
    // scalar bisection for the 17th-smallest composite key (ballot counts)
    ull lo = 0ULL, hi = 0x4100000000000000ULL;   // dd < 2^17 guaranteed
    while (lo < hi) {
        const ull mid = lo + ((hi - lo) >> 1);
        int cnt = 0;
#pragma unroll
        for (int b = 0; b < 4; ++b) cnt += __popcll(__ballot(key[b] <= mid));
        if (cnt >= NSLOT) hi = mid; else lo = mid + 1;
    }
    // emit the 17-set (order irrelevant for downstream set-invariant K4)
    int base = 0;
#pragma unroll
    for (int b = 0; b < 4; ++b) {
        const bool sel = (key[b] <= hi);
        const ull bal = __ballot(sel);
        const int pos = base + __popcll(bal & ((1ULL << l) - 1ULL));
        if (sel && pos < NSLOT) {
            fidx[(size_t)i * NSLOT + pos] = jidx[b];
            fscr[(size_t)i * NSLOT + pos] = dotf[b];
        }
        base += __popcll(bal);
    }
}

// ---------------- K4: mutual mask + sparse softmax + mix + normalize ----------------
__global__ void fcm_out_kernel(const float* __restrict__ feats,
                               const int* __restrict__ knn_idx,
                               const float* __restrict__ knn_scr,
                               float* __restrict__ out) {
    const int w    = threadIdx.x >> 6;
    const int lane = threadIdx.x & 63;
    const int i    = blockIdx.x * 4 + w;

    int jt = -1; float st = 0.f; bool valid = false;
    if (lane < NSLOT) {
        jt = knn_idx[(size_t)i * NSLOT + lane];
        st = knn_scr[(size_t)i * NSLOT + lane];
        if (jt != i) {
            const int* nb = knn_idx + (size_t)jt * NSLOT;
#pragma unroll
            for (int s = 0; s < NSLOT; ++s) valid |= (nb[s] == i);
        }
    }
    float val = valid ? st : -INFINITY;
#pragma unroll
    for (int off = 32; off > 0; off >>= 1) val = fmaxf(val, __shfl_xor(val, off, 64));
    const float m  = fmaxf(1.0f, val);
    const float wt = valid ? expf(st - m) : 0.f;
    float ws = wt;
#pragma unroll
    for (int off = 32; off > 0; off >>= 1) ws += __shfl_xor(ws, off, 64);
    const float wdiag = expf(1.0f - m);
    const float inv   = 1.0f / (ws + wdiag);

    const float4 fi = *reinterpret_cast<const float4*>(feats + (size_t)i * DIM + lane * 4);
    float ax = fi.x * wdiag, ay = fi.y * wdiag, az = fi.z * wdiag, aw = fi.w * wdiag;
    for (int t = 0; t < NSLOT; ++t) {
        const float wtt = __shfl(wt, t, 64);
        const int   jj  = __shfl(jt, t, 64);
        if (wtt > 0.f) {
            const float4 fj = *reinterpret_cast<const float4*>(feats + (size_t)jj * DIM + lane * 4);
            ax = fmaf(wtt, fj.x, ax); ay = fmaf(wtt, fj.y, ay);
            az = fmaf(wtt, fj.z, az); aw = fmaf(wtt, fj.w, aw);
        }
    }
    const float ox = fmaf(ax, inv, fi.x), oy = fmaf(ay, inv, fi.y);
    const float oz = fmaf(az, inv, fi.z), ow = fmaf(aw, inv, fi.w);
    float nn = ox * ox + oy * oy + oz * oz + ow * ow;
#pragma unroll
    for (int off = 32; off > 0; off >>= 1) nn += __shfl_xor(nn, off, 64);
    const float scl = 1.0f / fmaxf(sqrtf(nn), 1e-12f);
    float4 o; o.x = ox * scl; o.y = oy * scl; o.z = oz * scl; o.w = ow * scl;
    *reinterpret_cast<float4*>(out + (size_t)i * DIM + lane * 4) = o;
}

extern "C" void kernel_launch(void* const* d_in, const int* in_sizes, int n_in,
                              void* d_out, int out_size, void* d_ws, size_t ws_size,
                              hipStream_t stream) {
    (void)in_sizes; (void)n_in; (void)out_size; (void)ws_size;
    const float* feats = (const float*)d_in[0];
    float* out = (float*)d_out;
    char* ws = (char*)d_ws;
    size_t off = 0;
    float*  sq    = (float*) (ws + off); off += NPTS * 4;                 // 32 KB
    float*  musig = (float*) (ws + off); off += 128;
    ushort* fbp   = (ushort*)(ws + off); off += (size_t)NPTS * DIM * 2;   // 4 MB packed
    int*    cand  = (int*)   (ws + off); off += (size_t)NPTS * CAP * 4;   // 8 MB
    int*    cnt_g = (int*)   (ws + off); off += NPTS * 4;
    int*    fidx  = (int*)   (ws + off); off += NPTS * NSLOT * 4;
    float*  fscr  = (float*) (ws + off); off += NPTS * NSLOT * 4;

    pack_kernel<<<NPTS / 64, 256, 0, stream>>>(feats, fbp, sq, cnt_g);
    stats_kernel<<<1, 1024, 0, stream>>>(sq, musig);
    gemm_select_kernel<<<(NPTS / 64) * 4, 512, 0, stream>>>(fbp, sq, musig, cand, cnt_g);
    fallback_kernel<<<64, 256, 0, stream>>>(feats, sq, cand, cnt_g);
    refine_kernel<<<NPTS / 4, 256, 0, stream>>>(feats, cand, cnt_g, fidx, fscr);
    fcm_out_kernel<<<NPTS / 4, 256, 0, stream>>>(feats, fidx, fscr, out);
}

// Round 18
// 154.292 us; speedup vs baseline: 20.7546x; 1.0791x over previous
//
#include <hip/hip_runtime.h>
#include <math.h>

// FCM mutual-kNN attention mixing. N=8192, D=256, K=16.
//   K1 pack:   feats -> fbp fragment order + fp64 row sqnorms + zero cnt_g
//   K1b stats: deterministic reduction of sq -> mu/var
//   K2 gemm:   A panel contiguous in LDS, B coalesced fragment stream,
//              barrier-free; threshold select -> packed LDS cbuf -> merge.
//   K2b fallback: detect + full-rescan repair of bad rows (expected none)
//   K3 refine: top-24 by packed key (32-bit ballot bisection, 64-bit midpoint)
//              -> fp64 dot only (dd = sqd_i + sqd_j - 2 dot, the np formula)
//              -> exact top-17 set via 64-bit composite-key bisection.
//   K4 out:    mutual mask + sparse softmax + mix + normalize
#define NPTS 8192
#define DIM  256
#define NSLOT 17
#define CAP  256
#define LCAP 48
#define RSEL 24
#define ZTH  (-2.45f)
typedef unsigned int uint;
typedef unsigned short ushort;
typedef unsigned long long ull;
typedef __attribute__((ext_vector_type(8))) short bf16x8;
typedef __attribute__((ext_vector_type(4))) float f32x4;

__device__ __forceinline__ ushort f2bf(float f) {
    uint x = __float_as_uint(f);
    return (ushort)((x + 0x7fffu + ((x >> 16) & 1u)) >> 16);
}

// ---------------- K1: pack feats -> fragment order + fp64 sqnorms + cnt_g=0 ----------------
__global__ void pack_kernel(const float* __restrict__ feats, ushort* __restrict__ fbp,
                            float* __restrict__ sq, double* __restrict__ sqd,
                            int* __restrict__ cnt_g) {
    const int cb = (blockIdx.x * 256 + threadIdx.x) >> 6;   // global wave id
    const int l  = threadIdx.x & 63;
    const int l15 = l & 15, lg = l >> 4;
    const float* src = feats + (size_t)(cb * 16 + l15) * DIM + lg * 8;
    ushort* dst = fbp + (size_t)cb * 4096 + l * 8;
    double pd = 0.0;
#pragma unroll
    for (int kb = 0; kb < 8; ++kb) {
        const float4 v0 = *reinterpret_cast<const float4*>(src + kb * 32);
        const float4 v1 = *reinterpret_cast<const float4*>(src + kb * 32 + 4);
        pd += (double)v0.x * v0.x + (double)v0.y * v0.y +
              (double)v0.z * v0.z + (double)v0.w * v0.w;
        pd += (double)v1.x * v1.x + (double)v1.y * v1.y +
              (double)v1.z * v1.z + (double)v1.w * v1.w;
        bf16x8 bv;
        bv[0] = (short)f2bf(v0.x); bv[1] = (short)f2bf(v0.y);
        bv[2] = (short)f2bf(v0.z); bv[3] = (short)f2bf(v0.w);
        bv[4] = (short)f2bf(v1.x); bv[5] = (short)f2bf(v1.y);
        bv[6] = (short)f2bf(v1.z); bv[7] = (short)f2bf(v1.w);
        *reinterpret_cast<bf16x8*>(dst + kb * 512) = bv;
    }
    pd += __shfl_xor(pd, 16, 64);
    pd += __shfl_xor(pd, 32, 64);
    if (lg == 0) {
        const int row = cb * 16 + l15;
        sq[row] = (float)pd; sqd[row] = pd; cnt_g[row] = 0;
    }
}

// ---------------- K1b: deterministic stats (mu, var) ----------------
__global__ void stats_kernel(const float* __restrict__ sq, float* __restrict__ musig) {
    __shared__ double s0s[16], s1s[16];
    const int t = threadIdx.x, lane = t & 63, w = t >> 6;
    double s0 = 0.0, s1 = 0.0;
    for (int r = t; r < NPTS; r += 1024) {
        const double v = (double)sq[r];
        s0 += v; s1 += v * v;
    }
#pragma unroll
    for (int off = 32; off > 0; off >>= 1) {
        s0 += __shfl_down(s0, off, 64);
        s1 += __shfl_down(s1, off, 64);
    }
    if (lane == 0) { s0s[w] = s0; s1s[w] = s1; }
    __syncthreads();
    if (t == 0) {
        double a0 = 0.0, a1 = 0.0;
#pragma unroll
        for (int q = 0; q < 16; ++q) { a0 += s0s[q]; a1 += s1s[q]; }
        const double mu = a0 / NPTS;
        const double var = a1 / NPTS - mu * mu;
        musig[0] = (float)mu;
        musig[1] = (float)fmax(var, 1.0);
    }
}

// ---------------- K2: barrier-free MFMA GEMM + fused threshold select ----------------
// [round-15 verbatim] 512 thr = 8 waves. Block: 64 rows x 2048-col quarter.
__global__ __launch_bounds__(512, 2) void gemm_select_kernel(
    const ushort* __restrict__ fbp, const float* __restrict__ sq,
    const float* __restrict__ musig, int* __restrict__ cand, int* __restrict__ cnt_g) {
    __shared__ ushort As[16384];         // 32 KB fragment-ordered A panel
    __shared__ int    cbuf[64][LCAP];    // 12 KB packed (keyq<<13)|idx
    __shared__ float  Ts[64], sqi_s[64];
    __shared__ int    cnt[64];
    __shared__ int    base_s[64], n_s[64];

    const int tid = threadIdx.x;
    const int w   = tid >> 6;
    const int l   = tid & 63;
    const int l15 = l & 15, lg = l >> 4;
    const int rowblk = (blockIdx.x >> 3) * 2 + (blockIdx.x & 1);
    const int row0   = rowblk * 64;
    const int Jbase  = ((blockIdx.x & 7) >> 1) * 2048;

    if (tid < 64) {
        const float mu  = musig[0];
        const float var = musig[1];
        const float qi  = sq[row0 + tid];
        sqi_s[tid] = qi;
        Ts[tid]    = qi + mu + ZTH * sqrtf(var + 4.f * qi);
        cnt[tid]   = 0;
    }
    {   // stage A panel: straight 32KB copy (4 colblks of fbp)
        const ushort* src = fbp + (size_t)(row0 >> 4) * 4096;
#pragma unroll
        for (int s = 0; s < 4; ++s) {
            const int idx = tid + s * 512;
            *reinterpret_cast<bf16x8*>(As + idx * 8) =
                *reinterpret_cast<const bf16x8*>(src + (size_t)idx * 8);
        }
    }
    __syncthreads();                     // the ONLY barrier before the merge

    const int gcol = w * 32;
    const ushort* bp = fbp + (size_t)((Jbase >> 4) + w * 2) * 4096 + l * 8;

    bf16x8 bb[2][2];
#pragma unroll
    for (int cf = 0; cf < 2; ++cf)
        bb[0][cf] = *reinterpret_cast<const bf16x8*>(bp + cf * 4096);

    for (int tile = 0; tile < 8; ++tile) {
        f32x4 acc[4][2];
#pragma unroll
        for (int mf = 0; mf < 4; ++mf) {
            acc[mf][0] = (f32x4){0.f, 0.f, 0.f, 0.f};
            acc[mf][1] = (f32x4){0.f, 0.f, 0.f, 0.f};
        }
#pragma unroll
        for (int ks = 0; ks < 8; ++ks) {
            const int cur = ks & 1;
            if (tile < 7 || ks < 7) {    // prefetch next fragment pair
                const int ntile = (ks == 7) ? tile + 1 : tile;
                const int nks   = (ks == 7) ? 0 : ks + 1;
#pragma unroll
                for (int cf = 0; cf < 2; ++cf)
                    bb[cur ^ 1][cf] = *reinterpret_cast<const bf16x8*>(
                        bp + (size_t)ntile * 65536 + cf * 4096 + nks * 512);
            }
            bf16x8 af[4];
#pragma unroll
            for (int mf = 0; mf < 4; ++mf)
                af[mf] = *reinterpret_cast<const bf16x8*>(
                    As + ((mf * 8 + ks) * 64 + l) * 8);
#pragma unroll
            for (int mf = 0; mf < 4; ++mf) {
                acc[mf][0] = __builtin_amdgcn_mfma_f32_16x16x32_bf16(af[mf], bb[cur][0], acc[mf][0], 0, 0, 0);
                acc[mf][1] = __builtin_amdgcn_mfma_f32_16x16x32_bf16(af[mf], bb[cur][1], acc[mf][1], 0, 0, 0);
            }
        }
        // ---- per-tile epilogue: threshold select, packed into LDS cbuf ----
        const int Jt = Jbase + tile * 256;
        float sqc[2];
#pragma unroll
        for (int cf = 0; cf < 2; ++cf) sqc[cf] = sq[Jt + gcol + cf * 16 + l15];
#pragma unroll
        for (int mf = 0; mf < 4; ++mf)
#pragma unroll
            for (int cf = 0; cf < 2; ++cf)
#pragma unroll
                for (int r = 0; r < 4; ++r) {
                    const int row = mf * 16 + lg * 4 + r;
                    const float tt = Ts[row];
                    const float key = sqi_s[row] + sqc[cf] - 2.f * acc[mf][cf][r];
                    if (key < tt) {
                        const int kq2 = min((int)((tt - key) * 4096.f), 524287);
                        const uint val = ((uint)max(kq2, 0) << 13) |
                                         (uint)(Jt + gcol + cf * 16 + l15);
                        const int pos = atomicAdd(&cnt[row], 1);
                        if (pos < LCAP) cbuf[row][pos] = (int)val;
                    }
                }
    }
    __syncthreads();
    if (tid < 64) {
        const int local = cnt[tid];
        const int n = min(local, LCAP);
        const int add = (local > LCAP) ? (n + (1 << 20)) : n;   // poison on overflow
        base_s[tid] = atomicAdd(&cnt_g[row0 + tid], add);
        n_s[tid] = n;
    }
    __syncthreads();
    for (int s = tid; s < 64 * LCAP; s += 512) {
        const int r = s / LCAP, k2 = s - r * LCAP;
        if (k2 < n_s[r]) {
            const int b = base_s[r] + k2;
            if (b < CAP) cand[(size_t)(row0 + r) * CAP + b] = cbuf[r][k2];
        }
    }
}

// ---------------- K2b: detect + repair bad rows (expected none) ----------------
__global__ void fallback_kernel(const float* __restrict__ feats, const float* __restrict__ sq,
                                int* __restrict__ cand, int* __restrict__ cnt_g) {
    __shared__ float fi_s[DIM];
    __shared__ float keys[NPTS];
    __shared__ float rkey[4];
    __shared__ int   rid[4];
    const int t = threadIdx.x;
    for (int row = blockIdx.x; row < NPTS; row += gridDim.x) {
        const int v = cnt_g[row];
        if (v >= NSLOT && v <= CAP) continue;
        fi_s[t] = feats[(size_t)row * DIM + t];
        __syncthreads();
        const float sqi = sq[row];
        for (int p = 0; p < NPTS / 256; ++p) {
            const int jj = p * 256 + t;
            const float* fj = feats + (size_t)jj * DIM;
            float d = 0.f;
            for (int dq = 0; dq < DIM / 4; ++dq) {
                const float4 b4 = *reinterpret_cast<const float4*>(fj + dq * 4);
                const float4 a4 = *reinterpret_cast<const float4*>(&fi_s[dq * 4]);
                d = fmaf(a4.x, b4.x, fmaf(a4.y, b4.y, fmaf(a4.z, b4.z, fmaf(a4.w, b4.w, d))));
            }
            keys[jj] = sqi + sq[jj] - 2.f * d;
        }
        __syncthreads();
        for (int r = 0; r < 64; ++r) {
            float bk = INFINITY; int bj = 0x7fffffff;
            for (int p = 0; p < NPTS / 256; ++p) {
                const int jj = p * 256 + t;
                const float kv = keys[jj];
                if (kv < bk || (kv == bk && jj < bj)) { bk = kv; bj = jj; }
            }
#pragma unroll
            for (int off = 1; off <= 32; off <<= 1) {
                const float ok = __shfl_xor(bk, off, 64);
                const int   oj = __shfl_xor(bj, off, 64);
                if (ok < bk || (ok == bk && oj < bj)) { bk = ok; bj = oj; }
            }
            if ((t & 63) == 0) { rkey[t >> 6] = bk; rid[t >> 6] = bj; }
            __syncthreads();
            float fk = rkey[0]; int fj2 = rid[0];
#pragma unroll
            for (int q = 1; q < 4; ++q)
                if (rkey[q] < fk || (rkey[q] == fk && rid[q] < fj2)) { fk = rkey[q]; fj2 = rid[q]; }
            if (t == 0) {   // rank-ordered packed key (idx in low 13 bits)
                cand[(size_t)row * CAP + r] = (int)(((uint)(524287 - r) << 13) | (uint)fj2);
                keys[fj2] = INFINITY;
            }
            __syncthreads();
        }
        if (t == 0) cnt_g[row] = 64;
        __syncthreads();
    }
}

// ---------------- K3: refine v3 (64-bit-safe bisection midpoints) ----------------
__global__ __launch_bounds__(256) void refine_kernel(
    const float* __restrict__ feats, const double* __restrict__ sqd,
    const int* __restrict__ cand, const int* __restrict__ cnt_g,
    int* __restrict__ fidx, float* __restrict__ fscr) {
    __shared__ float fi_s[4][DIM];
    __shared__ int   sel_s[4][RSEL];
    const int w = threadIdx.x >> 6, l = threadIdx.x & 63;
    const int i = blockIdx.x * 4 + w;
    *reinterpret_cast<float4*>(&fi_s[w][l * 4]) =
        *reinterpret_cast<const float4*>(feats + (size_t)i * DIM + l * 4);
    __syncthreads();                     // only barrier; waves diverge after
    const int nc   = min(cnt_g[i], CAP);
    const int want = min(nc, RSEL);
    const int* crow = cand + (size_t)i * CAP;
    uint pk[4]; bool act[4];
#pragma unroll
    for (int b = 0; b < 4; ++b) {
        const int c = b * 64 + l;
        act[b] = (c < nc);
        pk[b]  = act[b] ? (uint)crow[c] : 0u;
    }
    // (1) bisect: largest T with count(act && pk >= T) >= want.
    // Midpoint in 64-bit: (lo + hi + 1) >> 1 would overflow uint32.
    uint lo = 0u, hi = 0xffffffffu;
    while (lo < hi) {
        const uint mid = (uint)(((ull)lo + (ull)hi + 1ULL) >> 1);
        int c = 0;
#pragma unroll
        for (int b = 0; b < 4; ++b) c += __popcll(__ballot(act[b] && pk[b] >= mid));
        if (c >= want) lo = mid; else hi = mid - 1u;
    }
    // (2) compact selected j-indices to sel_s[w][0..want)
    {
        int base = 0;
#pragma unroll
        for (int b = 0; b < 4; ++b) {
            const bool s = act[b] && pk[b] >= lo;
            const ull bal = __ballot(s);
            const int pos = base + __popcll(bal & ((1ULL << l) - 1ULL));
            if (s && pos < RSEL) sel_s[w][pos] = (int)(pk[b] & 8191u);
            base += __popcll(bal);
        }
    }
    // (3) fp64 dot for lanes < want (gather one row per active lane)
    const bool mine = (l < want);
    const int  j    = mine ? sel_s[w][l] : i;
    double dot0 = 0.0, dot1 = 0.0, dot2 = 0.0, dot3 = 0.0;
    if (mine) {
        const float* fj = feats + (size_t)j * DIM;
#pragma unroll 8
        for (int dq = 0; dq < DIM / 8; ++dq) {
            const float4 a0 = *reinterpret_cast<const float4*>(&fi_s[w][dq * 8]);
            const float4 a1 = *reinterpret_cast<const float4*>(&fi_s[w][dq * 8 + 4]);
            const float4 b0 = *reinterpret_cast<const float4*>(fj + dq * 8);
            const float4 b1 = *reinterpret_cast<const float4*>(fj + dq * 8 + 4);
            dot0 += (double)a0.x * b0.x + (double)a0.y * b0.y;
            dot1 += (double)a0.z * b0.z + (double)a0.w * b0.w;
            dot2 += (double)a1.x * b1.x + (double)a1.y * b1.y;
            dot3 += (double)a1.z * b1.z + (double)a1.w * b1.w;
        }
    }
    const double dot = (dot0 + dot1) + (dot2 + dot3);
    const double dd  = sqd[i] + sqd[j] - 2.0 * dot;   // the np-reference formula
    // (4) 17-smallest by composite key (dd bits | idx); range < 2^62, no overflow
    const ull key = mine ? ((ull)(__double_as_longlong(fmax(dd, 0.0)) & ~8191LL)
                            | (ull)(uint)j)
                         : ~0ULL;
    ull klo = 0ULL, khi = 0x4330000000000000ULL;      // dd < 2^52 bound
    while (klo < khi) {
        const ull mid = klo + ((khi - klo) >> 1);
        const int c = __popcll(__ballot(key <= mid));
        if (c >= NSLOT) khi = mid; else klo = mid + 1ULL;
    }
    const bool s2 = (key <= khi);
    const ull bal = __ballot(s2);
    const int pos = __popcll(bal & ((1ULL << l) - 1ULL));
    if (s2 && pos < NSLOT) {
        fidx[(size_t)i * NSLOT + pos] = j;
        fscr[(size_t)i * NSLOT + pos] = (float)dot;
    }
}

// ---------------- K4: mutual mask + sparse softmax + mix + normalize ----------------
__global__ void fcm_out_kernel(const float* __restrict__ feats,
                               const int* __restrict__ knn_idx,
                               const float* __restrict__ knn_scr,
                               float* __restrict__ out) {
    const int w    = threadIdx.x >> 6;
    const int lane = threadIdx.x & 63;
    const int i    = blockIdx.x * 4 + w;

    int jt = -1; float st = 0.f; bool valid = false;
    if (lane < NSLOT) {
        jt = knn_idx[(size_t)i * NSLOT + lane];
        st = knn_scr[(size_t)i * NSLOT + lane];
        if (jt != i) {
            const int* nb = knn_idx + (size_t)jt * NSLOT;
#pragma unroll
            for (int s = 0; s < NSLOT; ++s) valid |= (nb[s] == i);
        }
    }
    float val = valid ? st : -INFINITY;
#pragma unroll
    for (int off = 32; off > 0; off >>= 1) val = fmaxf(val, __shfl_xor(val, off, 64));
    const float m  = fmaxf(1.0f, val);
    const float wt = valid ? expf(st - m) : 0.f;
    float ws = wt;
#pragma unroll
    for (int off = 32; off > 0; off >>= 1) ws += __shfl_xor(ws, off, 64);
    const float wdiag = expf(1.0f - m);
    const float inv   = 1.0f / (ws + wdiag);

    const float4 fi = *reinterpret_cast<const float4*>(feats + (size_t)i * DIM + lane * 4);
    float ax = fi.x * wdiag, ay = fi.y * wdiag, az = fi.z * wdiag, aw = fi.w * wdiag;
    for (int t = 0; t < NSLOT; ++t) {
        const float wtt = __shfl(wt, t, 64);
        const int   jj  = __shfl(jt, t, 64);
        if (wtt > 0.f) {
            const float4 fj = *reinterpret_cast<const float4*>(feats + (size_t)jj * DIM + lane * 4);
            ax = fmaf(wtt, fj.x, ax); ay = fmaf(wtt, fj.y, ay);
            az = fmaf(wtt, fj.z, az); aw = fmaf(wtt, fj.w, aw);
        }
    }
    const float ox = fmaf(ax, inv, fi.x), oy = fmaf(ay, inv, fi.y);
    const float oz = fmaf(az, inv, fi.z), ow = fmaf(aw, inv, fi.w);
    float nn = ox * ox + oy * oy + oz * oz + ow * ow;
#pragma unroll
    for (int off = 32; off > 0; off >>= 1) nn += __shfl_xor(nn, off, 64);
    const float scl = 1.0f / fmaxf(sqrtf(nn), 1e-12f);
    float4 o; o.x = ox * scl; o.y = oy * scl; o.z = oz * scl; o.w = ow * scl;
    *reinterpret_cast<float4*>(out + (size_t)i * DIM + lane * 4) = o;
}

extern "C" void kernel_launch(void* const* d_in, const int* in_sizes, int n_in,
                              void* d_out, int out_size, void* d_ws, size_t ws_size,
                              hipStream_t stream) {
    (void)in_sizes; (void)n_in; (void)out_size; (void)ws_size;
    const float* feats = (const float*)d_in[0];
    float* out = (float*)d_out;
    char* ws = (char*)d_ws;
    size_t off = 0;
    float*  sq    = (float*) (ws + off); off += NPTS * 4;                 // 32 KB
    double* sqd   = (double*)(ws + off); off += NPTS * 8;                 // 64 KB
    float*  musig = (float*) (ws + off); off += 128;
    ushort* fbp   = (ushort*)(ws + off); off += (size_t)NPTS * DIM * 2;   // 4 MB packed
    int*    cand  = (int*)   (ws + off); off += (size_t)NPTS * CAP * 4;   // 8 MB
    int*    cnt_g = (int*)   (ws + off); off += NPTS * 4;
    int*    fidx  = (int*)   (ws + off); off += NPTS * NSLOT * 4;
    float*  fscr  = (float*) (ws + off); off += NPTS * NSLOT * 4;

    pack_kernel<<<NPTS / 64, 256, 0, stream>>>(feats, fbp, sq, sqd, cnt_g);
    stats_kernel<<<1, 1024, 0, stream>>>(sq, musig);
    gemm_select_kernel<<<(NPTS / 64) * 4, 512, 0, stream>>>(fbp, sq, musig, cand, cnt_g);
    fallback_kernel<<<64, 256, 0, stream>>>(feats, sq, cand, cnt_g);
    refine_kernel<<<NPTS / 4, 256, 0, stream>>>(feats, sqd, cand, cnt_g, fidx, fscr);
    fcm_out_kernel<<<NPTS / 4, 256, 0, stream>>>(feats, fidx, fscr, out);
}

// Round 19
// 119.923 us; speedup vs baseline: 26.7028x; 1.2866x over previous
//
#include <hip/hip_runtime.h>
#include <math.h>

// FCM mutual-kNN attention mixing. N=8192, D=256, K=16.
//   K1 pack:   feats -> fbp fragment order + fp64 row sqnorms + zero cnt_g
//   K1b stats: deterministic reduction of sq -> mu/var
//   K2 gemm:   A panel contiguous in LDS, B coalesced fragment stream with
//              DEPTH-2 slot-reuse prefetch, barrier-free; threshold select.
//   K2b fallback: parallel scan for bad rows + full-rescan repair (expected 0)
//   K3 refine: top-24 by packed key -> fp64 dot (np formula) -> exact top-17
//   K4 out:    mutual mask + sparse softmax + mix + normalize
#define NPTS 8192
#define DIM  256
#define NSLOT 17
#define CAP  256
#define LCAP 48
#define RSEL 24
#define ZTH  (-2.45f)
typedef unsigned int uint;
typedef unsigned short ushort;
typedef unsigned long long ull;
typedef __attribute__((ext_vector_type(8))) short bf16x8;
typedef __attribute__((ext_vector_type(4))) float f32x4;

__device__ __forceinline__ ushort f2bf(float f) {
    uint x = __float_as_uint(f);
    return (ushort)((x + 0x7fffu + ((x >> 16) & 1u)) >> 16);
}

// ---------------- K1: pack feats -> fragment order + fp64 sqnorms + cnt_g=0 ----------------
__global__ void pack_kernel(const float* __restrict__ feats, ushort* __restrict__ fbp,
                            float* __restrict__ sq, double* __restrict__ sqd,
                            int* __restrict__ cnt_g) {
    const int cb = (blockIdx.x * 256 + threadIdx.x) >> 6;   // global wave id
    const int l  = threadIdx.x & 63;
    const int l15 = l & 15, lg = l >> 4;
    const float* src = feats + (size_t)(cb * 16 + l15) * DIM + lg * 8;
    ushort* dst = fbp + (size_t)cb * 4096 + l * 8;
    double pd = 0.0;
#pragma unroll
    for (int kb = 0; kb < 8; ++kb) {
        const float4 v0 = *reinterpret_cast<const float4*>(src + kb * 32);
        const float4 v1 = *reinterpret_cast<const float4*>(src + kb * 32 + 4);
        pd += (double)v0.x * v0.x + (double)v0.y * v0.y +
              (double)v0.z * v0.z + (double)v0.w * v0.w;
        pd += (double)v1.x * v1.x + (double)v1.y * v1.y +
              (double)v1.z * v1.z + (double)v1.w * v1.w;
        bf16x8 bv;
        bv[0] = (short)f2bf(v0.x); bv[1] = (short)f2bf(v0.y);
        bv[2] = (short)f2bf(v0.z); bv[3] = (short)f2bf(v0.w);
        bv[4] = (short)f2bf(v1.x); bv[5] = (short)f2bf(v1.y);
        bv[6] = (short)f2bf(v1.z); bv[7] = (short)f2bf(v1.w);
        *reinterpret_cast<bf16x8*>(dst + kb * 512) = bv;
    }
    pd += __shfl_xor(pd, 16, 64);
    pd += __shfl_xor(pd, 32, 64);
    if (lg == 0) {
        const int row = cb * 16 + l15;
        sq[row] = (float)pd; sqd[row] = pd; cnt_g[row] = 0;
    }
}

// ---------------- K1b: deterministic stats (mu, var) ----------------
__global__ void stats_kernel(const float* __restrict__ sq, float* __restrict__ musig) {
    __shared__ double s0s[16], s1s[16];
    const int t = threadIdx.x, lane = t & 63, w = t >> 6;
    double s0 = 0.0, s1 = 0.0;
    for (int r = t; r < NPTS; r += 1024) {
        const double v = (double)sq[r];
        s0 += v; s1 += v * v;
    }
#pragma unroll
    for (int off = 32; off > 0; off >>= 1) {
        s0 += __shfl_down(s0, off, 64);
        s1 += __shfl_down(s1, off, 64);
    }
    if (lane == 0) { s0s[w] = s0; s1s[w] = s1; }
    __syncthreads();
    if (t == 0) {
        double a0 = 0.0, a1 = 0.0;
#pragma unroll
        for (int q = 0; q < 16; ++q) { a0 += s0s[q]; a1 += s1s[q]; }
        const double mu = a0 / NPTS;
        const double var = a1 / NPTS - mu * mu;
        musig[0] = (float)mu;
        musig[1] = (float)fmax(var, 1.0);
    }
}

// ---------------- K2: barrier-free MFMA GEMM + fused threshold select ----------------
// 512 thr = 8 waves. Block: 64 rows x 2048-col quarter. Depth-2 B prefetch:
// per step, MFMA(bb[ks&1]) first, then load frag(c+2) into the SAME slot.
__global__ __launch_bounds__(512, 2) void gemm_select_kernel(
    const ushort* __restrict__ fbp, const float* __restrict__ sq,
    const float* __restrict__ musig, int* __restrict__ cand, int* __restrict__ cnt_g) {
    __shared__ ushort As[16384];         // 32 KB fragment-ordered A panel
    __shared__ int    cbuf[64][LCAP];    // 12 KB packed (keyq<<13)|idx
    __shared__ float  Ts[64], sqi_s[64];
    __shared__ int    cnt[64];
    __shared__ int    base_s[64], n_s[64];

    const int tid = threadIdx.x;
    const int w   = tid >> 6;
    const int l   = tid & 63;
    const int l15 = l & 15, lg = l >> 4;
    const int rowblk = (blockIdx.x >> 3) * 2 + (blockIdx.x & 1);
    const int row0   = rowblk * 64;
    const int Jbase  = ((blockIdx.x & 7) >> 1) * 2048;

    if (tid < 64) {
        const float mu  = musig[0];
        const float var = musig[1];
        const float qi  = sq[row0 + tid];
        sqi_s[tid] = qi;
        Ts[tid]    = qi + mu + ZTH * sqrtf(var + 4.f * qi);
        cnt[tid]   = 0;
    }
    {   // stage A panel: straight 32KB copy (4 colblks of fbp)
        const ushort* src = fbp + (size_t)(row0 >> 4) * 4096;
#pragma unroll
        for (int s = 0; s < 4; ++s) {
            const int idx = tid + s * 512;
            *reinterpret_cast<bf16x8*>(As + idx * 8) =
                *reinterpret_cast<const bf16x8*>(src + (size_t)idx * 8);
        }
    }
    __syncthreads();                     // the ONLY barrier before the merge

    const int gcol = w * 32;
    const ushort* bp = fbp + (size_t)((Jbase >> 4) + w * 2) * 4096 + l * 8;

    bf16x8 bb[2][2];
#pragma unroll
    for (int cf = 0; cf < 2; ++cf) {
        bb[0][cf] = *reinterpret_cast<const bf16x8*>(bp + cf * 4096);          // chunk 0
        bb[1][cf] = *reinterpret_cast<const bf16x8*>(bp + cf * 4096 + 512);    // chunk 1
    }

    for (int tile = 0; tile < 8; ++tile) {
        f32x4 acc[4][2];
#pragma unroll
        for (int mf = 0; mf < 4; ++mf) {
            acc[mf][0] = (f32x4){0.f, 0.f, 0.f, 0.f};
            acc[mf][1] = (f32x4){0.f, 0.f, 0.f, 0.f};
        }
#pragma unroll
        for (int ks = 0; ks < 8; ++ks) {
            const int cur = ks & 1;
            bf16x8 af[4];
#pragma unroll
            for (int mf = 0; mf < 4; ++mf)
                af[mf] = *reinterpret_cast<const bf16x8*>(
                    As + ((mf * 8 + ks) * 64 + l) * 8);
#pragma unroll
            for (int mf = 0; mf < 4; ++mf) {
                acc[mf][0] = __builtin_amdgcn_mfma_f32_16x16x32_bf16(af[mf], bb[cur][0], acc[mf][0], 0, 0, 0);
                acc[mf][1] = __builtin_amdgcn_mfma_f32_16x16x32_bf16(af[mf], bb[cur][1], acc[mf][1], 0, 0, 0);
            }
            // depth-2 prefetch: frag(c+2) into the slot just consumed
            if (tile < 7 || ks < 6) {
                const int ntile = (ks >= 6) ? tile + 1 : tile;
                const int nks   = (ks + 2) & 7;
#pragma unroll
                for (int cf = 0; cf < 2; ++cf)
                    bb[cur][cf] = *reinterpret_cast<const bf16x8*>(
                        bp + (size_t)ntile * 65536 + cf * 4096 + nks * 512);
            }
        }
        // ---- per-tile epilogue: threshold select, packed into LDS cbuf ----
        const int Jt = Jbase + tile * 256;
        float sqc[2];
#pragma unroll
        for (int cf = 0; cf < 2; ++cf) sqc[cf] = sq[Jt + gcol + cf * 16 + l15];
#pragma unroll
        for (int mf = 0; mf < 4; ++mf)
#pragma unroll
            for (int cf = 0; cf < 2; ++cf)
#pragma unroll
                for (int r = 0; r < 4; ++r) {
                    const int row = mf * 16 + lg * 4 + r;
                    const float tt = Ts[row];
                    const float key = sqi_s[row] + sqc[cf] - 2.f * acc[mf][cf][r];
                    if (key < tt) {
                        const int kq2 = min((int)((tt - key) * 4096.f), 524287);
                        const uint val = ((uint)max(kq2, 0) << 13) |
                                         (uint)(Jt + gcol + cf * 16 + l15);
                        const int pos = atomicAdd(&cnt[row], 1);
                        if (pos < LCAP) cbuf[row][pos] = (int)val;
                    }
                }
    }
    __syncthreads();
    if (tid < 64) {
        const int local = cnt[tid];
        const int n = min(local, LCAP);
        const int add = (local > LCAP) ? (n + (1 << 20)) : n;   // poison on overflow
        base_s[tid] = atomicAdd(&cnt_g[row0 + tid], add);
        n_s[tid] = n;
    }
    __syncthreads();
    for (int s = tid; s < 64 * LCAP; s += 512) {
        const int r = s / LCAP, k2 = s - r * LCAP;
        if (k2 < n_s[r]) {
            const int b = base_s[r] + k2;
            if (b < CAP) cand[(size_t)(row0 + r) * CAP + b] = cbuf[r][k2];
        }
    }
}

// ---------------- K2b: parallel bad-row scan + repair (expected none) ----------------
// 32 blocks x 256 thr: each thread checks exactly one row (coalesced), bad rows
// compacted to LDS and repaired by the whole block via full rescan.
__global__ void fallback_kernel(const float* __restrict__ feats, const float* __restrict__ sq,
                                int* __restrict__ cand, int* __restrict__ cnt_g) {
    __shared__ float fi_s[DIM];
    __shared__ float keys[NPTS];
    __shared__ float rkey[4];
    __shared__ int   rid[4];
    __shared__ int   badlist[256];
    __shared__ int   nbad_s;
    const int t = threadIdx.x;
    if (t == 0) nbad_s = 0;
    __syncthreads();
    {
        const int myrow = blockIdx.x * 256 + t;
        const int v = cnt_g[myrow];
        if (v < NSLOT || v > CAP) badlist[atomicAdd(&nbad_s, 1)] = myrow;
    }
    __syncthreads();
    const int nb = nbad_s;
    for (int bi = 0; bi < nb; ++bi) {
        const int row = badlist[bi];
        fi_s[t] = feats[(size_t)row * DIM + t];
        __syncthreads();
        const float sqi = sq[row];
        for (int p = 0; p < NPTS / 256; ++p) {
            const int jj = p * 256 + t;
            const float* fj = feats + (size_t)jj * DIM;
            float d = 0.f;
            for (int dq = 0; dq < DIM / 4; ++dq) {
                const float4 b4 = *reinterpret_cast<const float4*>(fj + dq * 4);
                const float4 a4 = *reinterpret_cast<const float4*>(&fi_s[dq * 4]);
                d = fmaf(a4.x, b4.x, fmaf(a4.y, b4.y, fmaf(a4.z, b4.z, fmaf(a4.w, b4.w, d))));
            }
            keys[jj] = sqi + sq[jj] - 2.f * d;
        }
        __syncthreads();
        for (int r = 0; r < 64; ++r) {
            float bk = INFINITY; int bj = 0x7fffffff;
            for (int p = 0; p < NPTS / 256; ++p) {
                const int jj = p * 256 + t;
                const float kv = keys[jj];
                if (kv < bk || (kv == bk && jj < bj)) { bk = kv; bj = jj; }
            }
#pragma unroll
            for (int off = 1; off <= 32; off <<= 1) {
                const float ok = __shfl_xor(bk, off, 64);
                const int   oj = __shfl_xor(bj, off, 64);
                if (ok < bk || (ok == bk && oj < bj)) { bk = ok; bj = oj; }
            }
            if ((t & 63) == 0) { rkey[t >> 6] = bk; rid[t >> 6] = bj; }
            __syncthreads();
            float fk = rkey[0]; int fj2 = rid[0];
#pragma unroll
            for (int q = 1; q < 4; ++q)
                if (rkey[q] < fk || (rkey[q] == fk && rid[q] < fj2)) { fk = rkey[q]; fj2 = rid[q]; }
            if (t == 0) {   // rank-ordered packed key (idx in low 13 bits)
                cand[(size_t)row * CAP + r] = (int)(((uint)(524287 - r) << 13) | (uint)fj2);
                keys[fj2] = INFINITY;
            }
            __syncthreads();
        }
        if (t == 0) cnt_g[row] = 64;
        __syncthreads();
    }
}

// ---------------- K3: refine v3 (64-bit-safe bisection midpoints) ----------------
__global__ __launch_bounds__(256) void refine_kernel(
    const float* __restrict__ feats, const double* __restrict__ sqd,
    const int* __restrict__ cand, const int* __restrict__ cnt_g,
    int* __restrict__ fidx, float* __restrict__ fscr) {
    __shared__ float fi_s[4][DIM];
    __shared__ int   sel_s[4][RSEL];
    const int w = threadIdx.x >> 6, l = threadIdx.x & 63;
    const int i = blockIdx.x * 4 + w;
    *reinterpret_cast<float4*>(&fi_s[w][l * 4]) =
        *reinterpret_cast<const float4*>(feats + (size_t)i * DIM + l * 4);
    __syncthreads();                     // only barrier; waves diverge after
    const int nc   = min(cnt_g[i], CAP);
    const int want = min(nc, RSEL);
    const int* crow = cand + (size_t)i * CAP;
    uint pk[4]; bool act[4];
#pragma unroll
    for (int b = 0; b < 4; ++b) {
        const int c = b * 64 + l;
        act[b] = (c < nc);
        pk[b]  = act[b] ? (uint)crow[c] : 0u;
    }
    // (1) bisect: largest T with count(act && pk >= T) >= want (64-bit midpoint)
    uint lo = 0u, hi = 0xffffffffu;
    while (lo < hi) {
        const uint mid = (uint)(((ull)lo + (ull)hi + 1ULL) >> 1);
        int c = 0;
#pragma unroll
        for (int b = 0; b < 4; ++b) c += __popcll(__ballot(act[b] && pk[b] >= mid));
        if (c >= want) lo = mid; else hi = mid - 1u;
    }
    // (2) compact selected j-indices to sel_s[w][0..want)
    {
        int base = 0;
#pragma unroll
        for (int b = 0; b < 4; ++b) {
            const bool s = act[b] && pk[b] >= lo;
            const ull bal = __ballot(s);
            const int pos = base + __popcll(bal & ((1ULL << l) - 1ULL));
            if (s && pos < RSEL) sel_s[w][pos] = (int)(pk[b] & 8191u);
            base += __popcll(bal);
        }
    }
    // (3) fp64 dot for lanes < want
    const bool mine = (l < want);
    const int  j    = mine ? sel_s[w][l] : i;
    double dot0 = 0.0, dot1 = 0.0, dot2 = 0.0, dot3 = 0.0;
    if (mine) {
        const float* fj = feats + (size_t)j * DIM;
#pragma unroll 8
        for (int dq = 0; dq < DIM / 8; ++dq) {
            const float4 a0 = *reinterpret_cast<const float4*>(&fi_s[w][dq * 8]);
            const float4 a1 = *reinterpret_cast<const float4*>(&fi_s[w][dq * 8 + 4]);
            const float4 b0 = *reinterpret_cast<const float4*>(fj + dq * 8);
            const float4 b1 = *reinterpret_cast<const float4*>(fj + dq * 8 + 4);
            dot0 += (double)a0.x * b0.x + (double)a0.y * b0.y;
            dot1 += (double)a0.z * b0.z + (double)a0.w * b0.w;
            dot2 += (double)a1.x * b1.x + (double)a1.y * b1.y;
            dot3 += (double)a1.z * b1.z + (double)a1.w * b1.w;
        }
    }
    const double dot = (dot0 + dot1) + (dot2 + dot3);
    const double dd  = sqd[i] + sqd[j] - 2.0 * dot;   // the np-reference formula
    // (4) 17-smallest by composite key (dd bits | idx)
    const ull key = mine ? ((ull)(__double_as_longlong(fmax(dd, 0.0)) & ~8191LL)
                            | (ull)(uint)j)
                         : ~0ULL;
    ull klo = 0ULL, khi = 0x4330000000000000ULL;
    while (klo < khi) {
        const ull mid = klo + ((khi - klo) >> 1);
        const int c = __popcll(__ballot(key <= mid));
        if (c >= NSLOT) khi = mid; else klo = mid + 1ULL;
    }
    const bool s2 = (key <= khi);
    const ull bal = __ballot(s2);
    const int pos = __popcll(bal & ((1ULL << l) - 1ULL));
    if (s2 && pos < NSLOT) {
        fidx[(size_t)i * NSLOT + pos] = j;
        fscr[(size_t)i * NSLOT + pos] = (float)dot;
    }
}

// ---------------- K4: mutual mask + sparse softmax + mix + normalize ----------------
__global__ void fcm_out_kernel(const float* __restrict__ feats,
                               const int* __restrict__ knn_idx,
                               const float* __restrict__ knn_scr,
                               float* __restrict__ out) {
    const int w    = threadIdx.x >> 6;
    const int lane = threadIdx.x & 63;
    const int i    = blockIdx.x * 4 + w;

    int jt = -1; float st = 0.f; bool valid = false;
    if (lane < NSLOT) {
        jt = knn_idx[(size_t)i * NSLOT + lane];
        st = knn_scr[(size_t)i * NSLOT + lane];
        if (jt != i) {
            const int* nb = knn_idx + (size_t)jt * NSLOT;
#pragma unroll
            for (int s = 0; s < NSLOT; ++s) valid |= (nb[s] == i);
        }
    }
    float val = valid ? st : -INFINITY;
#pragma unroll
    for (int off = 32; off > 0; off >>= 1) val = fmaxf(val, __shfl_xor(val, off, 64));
    const float m  = fmaxf(1.0f, val);
    const float wt = valid ? expf(st - m) : 0.f;
    float ws = wt;
#pragma unroll
    for (int off = 32; off > 0; off >>= 1) ws += __shfl_xor(ws, off, 64);
    const float wdiag = expf(1.0f - m);
    const float inv   = 1.0f / (ws + wdiag);

    const float4 fi = *reinterpret_cast<const float4*>(feats + (size_t)i * DIM + lane * 4);
    float ax = fi.x * wdiag, ay = fi.y * wdiag, az = fi.z * wdiag, aw = fi.w * wdiag;
    for (int t = 0; t < NSLOT; ++t) {
        const float wtt = __shfl(wt, t, 64);
        const int   jj  = __shfl(jt, t, 64);
        if (wtt > 0.f) {
            const float4 fj = *reinterpret_cast<const float4*>(feats + (size_t)jj * DIM + lane * 4);
            ax = fmaf(wtt, fj.x, ax); ay = fmaf(wtt, fj.y, ay);
            az = fmaf(wtt, fj.z, az); aw = fmaf(wtt, fj.w, aw);
        }
    }
    const float ox = fmaf(ax, inv, fi.x), oy = fmaf(ay, inv, fi.y);
    const float oz = fmaf(az, inv, fi.z), ow = fmaf(aw, inv, fi.w);
    float nn = ox * ox + oy * oy + oz * oz + ow * ow;
#pragma unroll
    for (int off = 32; off > 0; off >>= 1) nn += __shfl_xor(nn, off, 64);
    const float scl = 1.0f / fmaxf(sqrtf(nn), 1e-12f);
    float4 o; o.x = ox * scl; o.y = oy * scl; o.z = oz * scl; o.w = ow * scl;
    *reinterpret_cast<float4*>(out + (size_t)i * DIM + lane * 4) = o;
}

extern "C" void kernel_launch(void* const* d_in, const int* in_sizes, int n_in,
                              void* d_out, int out_size, void* d_ws, size_t ws_size,
                              hipStream_t stream) {
    (void)in_sizes; (void)n_in; (void)out_size; (void)ws_size;
    const float* feats = (const float*)d_in[0];
    float* out = (float*)d_out;
    char* ws = (char*)d_ws;
    size_t off = 0;
    float*  sq    = (float*) (ws + off); off += NPTS * 4;                 // 32 KB
    double* sqd   = (double*)(ws + off); off += NPTS * 8;                 // 64 KB
    float*  musig = (float*) (ws + off); off += 128;
    ushort* fbp   = (ushort*)(ws + off); off += (size_t)NPTS * DIM * 2;   // 4 MB packed
    int*    cand  = (int*)   (ws + off); off += (size_t)NPTS * CAP * 4;   // 8 MB
    int*    cnt_g = (int*)   (ws + off); off += NPTS * 4;
    int*    fidx  = (int*)   (ws + off); off += NPTS * NSLOT * 4;
    float*  fscr  = (float*) (ws + off); off += NPTS * NSLOT * 4;

    pack_kernel<<<NPTS / 64, 256, 0, stream>>>(feats, fbp, sq, sqd, cnt_g);
    stats_kernel<<<1, 1024, 0, stream>>>(sq, musig);
    gemm_select_kernel<<<(NPTS / 64) * 4, 512, 0, stream>>>(fbp, sq, musig, cand, cnt_g);
    fallback_kernel<<<NPTS / 256, 256, 0, stream>>>(feats, sq, cand, cnt_g);
    refine_kernel<<<NPTS / 4, 256, 0, stream>>>(feats, sqd, cand, cnt_g, fidx, fscr);
    fcm_out_kernel<<<NPTS / 4, 256, 0, stream>>>(feats, fidx, fscr, out);
}